// Round 9
// baseline (1341.372 us; speedup 1.0000x reference)
//
#include <hip/hip_runtime.h>

#define B_  8
#define N_  4096
#define S_  1024
#define K_  64
#define CF_ 128
#define M_  (B_*S_*K_)   // 524288 rows per layer

typedef __attribute__((ext_vector_type(8))) short bshort8;
typedef __attribute__((ext_vector_type(4))) float f32x4;
typedef __attribute__((ext_vector_type(4))) int   i32x4;
typedef __attribute__((ext_vector_type(2))) float f32x2;

__device__ __forceinline__ unsigned short f2bf(float f){
  unsigned int u = __float_as_uint(f);
  u = u + 0x7FFFu + ((u >> 16) & 1u);      // RTNE
  return (unsigned short)(u >> 16);
}
__device__ __forceinline__ float bf2f(unsigned short h){
  return __uint_as_float(((unsigned int)h) << 16);
}

// ---------------------------------------------------------------------------
// FPS v6: one block (256 thr = 4 waves) per batch. r7 base (best measured:
// 785us) with ONE change: the per-iteration __syncthreads (full waitcnt drain,
// x1024) is replaced by an LDS generation-flag rendezvous.
//   - lane63/wave writes a 16B packet {gen, vbits, idx, gen} (gen duplicated
//     word0+word3 -> any torn write is detected) to parity buffer red[it&1][w]
//   - all threads spin-poll the 4 packets until both gen words == it
//   - parity double-buffer => the it+1 write never clobbers an unread it slot
//   - slots pre-initialized to -1 before the single initial __syncthreads
// Update math BITWISE-FROZEN (passing r4-r8): packed plain-rn sub/mul/add
// (contract off), fminf, strict-> ascending-index argmax, i=j*256+t.
// ---------------------------------------------------------------------------
#define DPP_PAIR_STEP(CTRL)                                                     \
  {                                                                             \
    int _vi = __builtin_amdgcn_update_dpp(__float_as_int(best), __float_as_int(best), (CTRL), 0xF, 0xF, false); \
    int _ii = __builtin_amdgcn_update_dpp(bidx, bidx, (CTRL), 0xF, 0xF, false); \
    float _ov = __int_as_float(_vi);                                            \
    bool _tk = (_ov > best) || (_ov == best && _ii < bidx);                     \
    best = _tk ? _ov : best;                                                    \
    bidx = _tk ? _ii : bidx;                                                    \
  }

__global__ __launch_bounds__(256) void fps_kernel(const float* __restrict__ xyz,
                                                  float* __restrict__ nx_out,
                                                  float* __restrict__ nx_ws){
#pragma clang fp contract(off)
  __shared__ float sx[N_], sy[N_], sz[N_];
  __shared__ int   sidx[S_];
  __shared__ alignas(16) int red[2][4][4];   // [parity][wave][{gen,v,i,gen}]
  const int b = blockIdx.x, t = threadIdx.x;
  const int lane = t & 63, w = t >> 6;      // 4 waves
  const float* xb = xyz + (size_t)b*N_*3;
  f32x2 px[8], py[8], pz[8], dist[8];
#pragma unroll
  for (int j=0;j<8;++j){
    int i0 = (2*j)*256 + t, i1 = (2*j+1)*256 + t;
    float x0=xb[i0*3+0], y0=xb[i0*3+1], z0=xb[i0*3+2];
    float x1=xb[i1*3+0], y1=xb[i1*3+1], z1=xb[i1*3+2];
    px[j] = (f32x2){x0,x1}; py[j] = (f32x2){y0,y1}; pz[j] = (f32x2){z0,z1};
    dist[j] = (f32x2){1e10f,1e10f};
    sx[i0]=x0; sy[i0]=y0; sz[i0]=z0;
    sx[i1]=x1; sy[i1]=y1; sz[i1]=z1;
  }
  if (t < 8) *(i32x4*)&red[t>>2][t&3][0] = (i32x4){-1,-1,-1,-1};
  __syncthreads();
  int farthest = 0;
  for (int it=0; it<S_; ++it){
    if (t==0) sidx[it] = farthest;
    float cx = sx[farthest], cy = sy[farthest], cz = sz[farthest];
    f32x2 cx2 = (f32x2){cx,cx}, cy2 = (f32x2){cy,cy}, cz2 = (f32x2){cz,cz};
    float best = -1.0f; int bidx = 0;
#pragma unroll
    for (int j=0;j<8;++j){
      // per-element: ((dx*dx)+(dy*dy))+(dz*dz), plain rn (contract off)
      f32x2 dx = px[j] - cx2;
      f32x2 dy = py[j] - cy2;
      f32x2 dz = pz[j] - cz2;
      f32x2 d  = (dx*dx + dy*dy) + dz*dz;
      f32x2 nd;
      nd.x = fminf(dist[j].x, d.x);
      nd.y = fminf(dist[j].y, d.y);
      dist[j] = nd;
      bool tk0 = nd.x > best;
      best = tk0 ? nd.x : best;
      bidx = tk0 ? ((2*j)*256 + t) : bidx;
      bool tk1 = nd.y > best;
      best = tk1 ? nd.y : best;
      bidx = tk1 ? ((2*j+1)*256 + t) : bidx;
    }
    // wave64 pair-reduce via DPP; lane 63 ends with the wave result
    DPP_PAIR_STEP(0xB1);   // quad_perm [1,0,3,2]  (xor 1)
    DPP_PAIR_STEP(0x4E);   // quad_perm [2,3,0,1]  (xor 2)
    DPP_PAIR_STEP(0x124);  // row_ror:4
    DPP_PAIR_STEP(0x128);  // row_ror:8
    DPP_PAIR_STEP(0x142);  // row_bcast:15
    DPP_PAIR_STEP(0x143);  // row_bcast:31
    const int buf = it & 1;
    if (lane == 63){
      *(i32x4*)&red[buf][w][0] = (i32x4){it, __float_as_int(best), bidx, it};
    }
    // LDS rendezvous: poll the 4 packets until gen words match this iteration
    i32x4 s0, s1, s2, s3;
    volatile i32x4* rp = (volatile i32x4*)&red[buf][0][0];
    for (;;){
      s0 = rp[0]; s1 = rp[1]; s2 = rp[2]; s3 = rp[3];
      if (s0[0]==it && s0[3]==it && s1[0]==it && s1[3]==it &&
          s2[0]==it && s2[3]==it && s3[0]==it && s3[3]==it) break;
    }
    float v0=__int_as_float(s0[1]), v1=__int_as_float(s1[1]);
    float v2=__int_as_float(s2[1]), v3=__int_as_float(s3[1]);
    int   i0=s0[2], i1=s1[2], i2=s2[2], i3=s3[2];
    // tree lex-max combine (associative; first-index tie-break preserved)
    bool t1 = (v1 > v0) || (v1 == v0 && i1 < i0);
    float va = t1 ? v1 : v0; int ia = t1 ? i1 : i0;
    bool t2 = (v3 > v2) || (v3 == v2 && i3 < i2);
    float vb = t2 ? v3 : v2; int ib = t2 ? i3 : i2;
    bool t3 = (vb > va) || (vb == va && ib < ia);
    farthest = t3 ? ib : ia;
  }
  __syncthreads();
  // write the 1024 selected centroids once, at the end
  for (int i=t; i<S_; i+=256){
    int id = sidx[i];
    size_t base = (size_t)(b*S_+i)*3;
    float vx=sx[id], vy=sy[id], vz=sz[id];
    nx_out[base+0]=vx; nx_out[base+1]=vy; nx_out[base+2]=vz;
    nx_ws[base+0]=vx;  nx_ws[base+1]=vy;  nx_ws[base+2]=vz;
  }
}

// ---------------------------------------------------------------------------
// Ball query: one wave per (b,s); ascending first-64 indices, pad with first.
// f64 membership (golden np ref evaluates in float64) — VERIFIED round 4.
// ---------------------------------------------------------------------------
__global__ __launch_bounds__(256) void qbp_kernel(const float* __restrict__ xyz,
                                                  const float* __restrict__ nx,
                                                  int* __restrict__ gi){
  const double R2 = 0.2*0.2;   // 0.04000000000000001 (f64)
  int gtid = blockIdx.x*256 + threadIdx.x;
  int wid = gtid >> 6, lane = gtid & 63;
  int b = wid >> 10, s = wid & 1023;
  const float* xb = xyz + (size_t)b*N_*3;
  const float* c  = nx + (size_t)(b*S_+s)*3;
  double cx=(double)c[0], cy=(double)c[1], cz=(double)c[2];
  double cc = cx*cx + cy*cy + cz*cz;
  int* g = gi + (size_t)(b*S_+s)*K_;
  int count = 0, first = -1;
  for (int ch=0; ch<64 && count<K_; ++ch){
    int i = ch*64 + lane;
    double x = (double)xb[i*3+0], y = (double)xb[i*3+1], z = (double)xb[i*3+2];
    double e  = cx*x + cy*y + cz*z;
    double pp = x*x + y*y + z*z;
    double d  = -2.0*e + cc + pp;
    bool keep = !(d > R2);
    unsigned long long bal = __ballot(keep);
    int pos = count + __builtin_popcountll(bal & ((1ull<<lane)-1ull));
    if (keep && pos < K_) g[pos] = i;
    if (first < 0 && bal) first = ch*64 + (int)__builtin_ctzll(bal);
    count += __builtin_popcountll(bal);
  }
  if (count < K_){
    int p = count + lane;
    if (p < K_) g[p] = first;
  }
}

// ---------------------------------------------------------------------------
// features (B,128,4096) f32 -> featT (B,4096,128) bf16
// ---------------------------------------------------------------------------
__global__ __launch_bounds__(256) void transpose_kernel(const float* __restrict__ f,
                                                        unsigned short* __restrict__ ft){
  __shared__ float tile[32][33];
  int b = blockIdx.z, ct = blockIdx.y, nt = blockIdx.x;
  int tx = threadIdx.x & 31, ty = threadIdx.x >> 5;
#pragma unroll
  for (int r=0; r<32; r+=8)
    tile[ty+r][tx] = f[((size_t)(b*128 + ct*32 + ty + r))*4096 + nt*32 + tx];
  __syncthreads();
#pragma unroll
  for (int r=0; r<32; r+=8){
    int n = nt*32 + ty + r, cc = ct*32 + tx;
    ft[((size_t)b*4096 + n)*128 + cc] = f2bf(tile[tx][ty+r]);
  }
}

// ---------------------------------------------------------------------------
// Weights -> bf16 [n][k]; layer-1 K permuted to [feat(0..127), dxyz(128..130), 0-pad..159]
// ---------------------------------------------------------------------------
__global__ void wprep_kernel(const float* __restrict__ W1, const float* __restrict__ W2,
                             const float* __restrict__ W3,
                             unsigned short* __restrict__ Wt1, unsigned short* __restrict__ Wt2,
                             unsigned short* __restrict__ Wt3){
  int t = blockIdx.x*blockDim.x + threadIdx.x;
  int stride = gridDim.x*blockDim.x;
  for (int idx=t; idx<128*160; idx+=stride){
    int n = idx/160, k = idx-(idx/160)*160;
    float v = 0.f;
    if (k < 128) v = W1[(k+3)*128 + n];
    else if (k < 131) v = W1[(k-128)*128 + n];
    Wt1[idx] = f2bf(v);
  }
  for (int idx=t; idx<128*128; idx+=stride){
    int n = idx>>7, k = idx&127;
    Wt2[idx] = f2bf(W2[k*128+n]);
  }
  for (int idx=t; idx<256*128; idx+=stride){
    int n = idx>>7, k = idx&127;
    Wt3[idx] = f2bf(W3[k*256+n]);
  }
}

// ---------------------------------------------------------------------------
// Fused recompute GEMM chain per 128-row slab, v2: single-barrier
// double-buffered chunk staging (stage ch+1 in VGPRs during MFMA of ch).
// PHASE 1: GEMM1 -> col sums1
// PHASE 2: GEMM1 -> BN1+ReLU(Y) -> GEMM2 -> col sums2
// PHASE 3: GEMM1 -> BN1 -> GEMM2 -> BN2 -> GEMM3 (2 N-halves) -> sums3+min/max
// ---------------------------------------------------------------------------
template<int PHASE>
__global__ __launch_bounds__(256,2) void mm_fused(
    const unsigned short* __restrict__ featT,
    const unsigned short* __restrict__ Wt1,
    const unsigned short* __restrict__ Wt2,
    const unsigned short* __restrict__ Wt3,
    const int* __restrict__ gi,
    const float* __restrict__ xyz,
    const float* __restrict__ nxyz,
    const float* __restrict__ ss1,
    const float* __restrict__ ss2,
    float* __restrict__ slots,
    float* __restrict__ minv,
    float* __restrict__ maxv)
{
  __shared__ alignas(16) unsigned short At[2][128*40];
  __shared__ alignas(16) unsigned short Bt[2][128*40];
  __shared__ alignas(16) unsigned short Y[(PHASE>=2)?(128*136):16];
  __shared__ int giL[128];

  const int t = threadIdx.x;
  const int mblk = blockIdx.x;
  const int b = mblk >> 9;                 // 512 slabs per batch
  const int lane = t&63, wave = t>>6;
  const int wm = wave>>1, wn = wave&1;
  const int lrow = lane&15, quad = lane>>4;
  const int slot = mblk & 63;

  if (t<128) giL[t] = gi[(size_t)mblk*128 + t];
  __syncthreads();

  f32x4 acc[4][4];
  const f32x4 z4 = {0.f,0.f,0.f,0.f};
#pragma unroll
  for (int i=0;i<4;++i)
#pragma unroll
    for (int j=0;j<4;++j) acc[i][j]=z4;

  // ---------------- GEMM1 (dbuf): A = gathered [feat|dxyz|pad], K=160 ------
  {
    bshort8 aV[2], bV[2];
#pragma unroll
    for (int half=0; half<2; ++half){
      int sl = t + half*256; int r = sl>>2, p = sl&3;
      bV[half] = *(const bshort8*)(Wt1 + r*160 + p*8);
      int i = giL[r];
      aV[half] = *(const bshort8*)(featT + ((size_t)b*N_ + i)*CF_ + p*8);
    }
#pragma unroll
    for (int half=0; half<2; ++half){
      int sl = t + half*256; int r = sl>>2, p = sl&3;
      *(bshort8*)&At[0][r*40+p*8] = aV[half];
      *(bshort8*)&Bt[0][r*40+p*8] = bV[half];
    }
    for (int ch=0; ch<5; ++ch){
      const int cur = ch & 1;
      __syncthreads();
      bshort8 af[4], bfr[4];
#pragma unroll
      for (int mt=0; mt<4; ++mt) af[mt]  = *(const bshort8*)&At[cur][(wm*64+mt*16+lrow)*40 + quad*8];
#pragma unroll
      for (int nt=0; nt<4; ++nt) bfr[nt] = *(const bshort8*)&Bt[cur][(wn*64+nt*16+lrow)*40 + quad*8];
      if (ch < 4){
        const int nch = ch + 1;
#pragma unroll
        for (int half=0; half<2; ++half){
          int sl = t + half*256; int r = sl>>2, p = sl&3;
          bV[half] = *(const bshort8*)(Wt1 + r*160 + nch*32 + p*8);
          if (nch < 4){
            int i = giL[r];
            aV[half] = *(const bshort8*)(featT + ((size_t)b*N_ + i)*CF_ + nch*32 + p*8);
          } else {
            union { bshort8 v; unsigned short u[8]; } o;
#pragma unroll
            for (int e=0;e<8;++e) o.u[e]=0;
            if (p==0){
              int i = giL[r];
              int s = ((mblk*128 + r) >> 6) & 1023;
              const float* pp = xyz  + ((size_t)b*N_ + i)*3;
              const float* qq = nxyz + (size_t)(b*S_ + s)*3;
              o.u[0] = f2bf(__fsub_rn(pp[0],qq[0]));
              o.u[1] = f2bf(__fsub_rn(pp[1],qq[1]));
              o.u[2] = f2bf(__fsub_rn(pp[2],qq[2]));
            }
            aV[half] = o.v;
          }
        }
      }
#pragma unroll
      for (int mt=0; mt<4; ++mt)
#pragma unroll
        for (int nt=0; nt<4; ++nt)
          acc[mt][nt] = __builtin_amdgcn_mfma_f32_16x16x32_bf16(af[mt], bfr[nt], acc[mt][nt], 0,0,0);
      if (ch < 4){
        const int nxt = cur ^ 1;
#pragma unroll
        for (int half=0; half<2; ++half){
          int sl = t + half*256; int r = sl>>2, p = sl&3;
          *(bshort8*)&At[nxt][r*40+p*8] = aV[half];
          *(bshort8*)&Bt[nxt][r*40+p*8] = bV[half];
        }
      }
    }
  }

  if constexpr (PHASE==1){
#pragma unroll
    for (int nt=0; nt<4; ++nt){
      float s=0.f, s2=0.f;
#pragma unroll
      for (int mt=0; mt<4; ++mt)
#pragma unroll
        for (int r=0; r<4; ++r){ float v=acc[mt][nt][r]; s+=v; s2=fmaf(v,v,s2); }
      s  += __shfl_xor(s,16,64);  s  += __shfl_xor(s,32,64);
      s2 += __shfl_xor(s2,16,64); s2 += __shfl_xor(s2,32,64);
      if (lane<16){
        int c = wn*64+nt*16+lane;
        atomicAdd(&slots[(slot*128+c)*2+0], s);
        atomicAdd(&slots[(slot*128+c)*2+1], s2);
      }
    }
    return;
  }

  if constexpr (PHASE>=2){
    // ---- BN1 + ReLU -> Y (C-layout: col=lane&15, row=quad*4+reg) ----
#pragma unroll
    for (int nt=0; nt<4; ++nt){
      int c = wn*64+nt*16+lrow;
      float sc = ss1[c], sh = ss1[128+c];
#pragma unroll
      for (int mt=0; mt<4; ++mt)
#pragma unroll
        for (int r=0; r<4; ++r){
          int row = wm*64+mt*16+quad*4+r;
          Y[row*136 + c] = f2bf(fmaxf(fmaf(acc[mt][nt][r], sc, sh), 0.f));
        }
    }

    // ---------------- GEMM2 (dbuf): A = Y (z1), K=128 ----------------
#pragma unroll
    for (int i=0;i<4;++i)
#pragma unroll
      for (int j=0;j<4;++j) acc[i][j]=z4;
    {
      bshort8 bV[2];
#pragma unroll
      for (int half=0; half<2; ++half){
        int sl = t + half*256; int r = sl>>2, p = sl&3;
        bV[half] = *(const bshort8*)(Wt2 + r*128 + p*8);
      }
#pragma unroll
      for (int half=0; half<2; ++half){
        int sl = t + half*256; int r = sl>>2, p = sl&3;
        *(bshort8*)&Bt[1][r*40+p*8] = bV[half];
      }
      for (int ch=0; ch<4; ++ch){
        const int cur = (ch & 1) ^ 1;
        __syncthreads();   // covers Y writes (first iter) + Bt[cur] staging
        bshort8 af[4], bfr[4];
#pragma unroll
        for (int mt=0; mt<4; ++mt) af[mt]  = *(const bshort8*)&Y[(wm*64+mt*16+lrow)*136 + ch*32 + quad*8];
#pragma unroll
        for (int nt=0; nt<4; ++nt) bfr[nt] = *(const bshort8*)&Bt[cur][(wn*64+nt*16+lrow)*40 + quad*8];
        if (ch < 3){
#pragma unroll
          for (int half=0; half<2; ++half){
            int sl = t + half*256; int r = sl>>2, p = sl&3;
            bV[half] = *(const bshort8*)(Wt2 + r*128 + (ch+1)*32 + p*8);
          }
        }
#pragma unroll
        for (int mt=0; mt<4; ++mt)
#pragma unroll
          for (int nt=0; nt<4; ++nt)
            acc[mt][nt] = __builtin_amdgcn_mfma_f32_16x16x32_bf16(af[mt], bfr[nt], acc[mt][nt], 0,0,0);
        if (ch < 3){
          const int nxt = cur ^ 1;
#pragma unroll
          for (int half=0; half<2; ++half){
            int sl = t + half*256; int r = sl>>2, p = sl&3;
            *(bshort8*)&Bt[nxt][r*40+p*8] = bV[half];
          }
        }
      }
    }
  }

  if constexpr (PHASE==2){
#pragma unroll
    for (int nt=0; nt<4; ++nt){
      float s=0.f, s2=0.f;
#pragma unroll
      for (int mt=0; mt<4; ++mt)
#pragma unroll
        for (int r=0; r<4; ++r){ float v=acc[mt][nt][r]; s+=v; s2=fmaf(v,v,s2); }
      s  += __shfl_xor(s,16,64);  s  += __shfl_xor(s,32,64);
      s2 += __shfl_xor(s2,16,64); s2 += __shfl_xor(s2,32,64);
      if (lane<16){
        int c = wn*64+nt*16+lane;
        atomicAdd(&slots[(slot*128+c)*2+0], s);
        atomicAdd(&slots[(slot*128+c)*2+1], s2);
      }
    }
    return;
  }

  if constexpr (PHASE==3){
    // ---- BN2 + ReLU -> Y (overwrite). Barrier: other waves may still be
    // doing their GEMM2 ch3 Y-frag reads.
    __syncthreads();
#pragma unroll
    for (int nt=0; nt<4; ++nt){
      int c = wn*64+nt*16+lrow;
      float sc = ss2[c], sh = ss2[128+c];
#pragma unroll
      for (int mt=0; mt<4; ++mt)
#pragma unroll
        for (int r=0; r<4; ++r){
          int row = wm*64+mt*16+quad*4+r;
          Y[row*136 + c] = f2bf(fmaxf(fmaf(acc[mt][nt][r], sc, sh), 0.f));
        }
    }

    // ---------------- GEMM3 (dbuf): A = Y (z2), Nout=256 in two halves -----
    for (int h=0; h<2; ++h){
#pragma unroll
      for (int i=0;i<4;++i)
#pragma unroll
        for (int j=0;j<4;++j) acc[i][j]=z4;
      bshort8 bV[2];
#pragma unroll
      for (int half=0; half<2; ++half){
        int sl = t + half*256; int r = sl>>2, p = sl&3;
        bV[half] = *(const bshort8*)(Wt3 + ((size_t)(h*128+r))*128 + p*8);
      }
#pragma unroll
      for (int half=0; half<2; ++half){
        int sl = t + half*256; int r = sl>>2, p = sl&3;
        *(bshort8*)&Bt[1][r*40+p*8] = bV[half];
      }
      for (int ch=0; ch<4; ++ch){
        const int cur = (ch & 1) ^ 1;
        __syncthreads();
        bshort8 af[4], bfr[4];
#pragma unroll
        for (int mt=0; mt<4; ++mt) af[mt]  = *(const bshort8*)&Y[(wm*64+mt*16+lrow)*136 + ch*32 + quad*8];
#pragma unroll
        for (int nt=0; nt<4; ++nt) bfr[nt] = *(const bshort8*)&Bt[cur][(wn*64+nt*16+lrow)*40 + quad*8];
        if (ch < 3){
#pragma unroll
          for (int half=0; half<2; ++half){
            int sl = t + half*256; int r = sl>>2, p = sl&3;
            bV[half] = *(const bshort8*)(Wt3 + ((size_t)(h*128+r))*128 + (ch+1)*32 + p*8);
          }
        }
#pragma unroll
        for (int mt=0; mt<4; ++mt)
#pragma unroll
          for (int nt=0; nt<4; ++nt)
            acc[mt][nt] = __builtin_amdgcn_mfma_f32_16x16x32_bf16(af[mt], bfr[nt], acc[mt][nt], 0,0,0);
        if (ch < 3){
          const int nxt = cur ^ 1;
#pragma unroll
          for (int half=0; half<2; ++half){
            int sl = t + half*256; int r = sl>>2, p = sl&3;
            *(bshort8*)&Bt[nxt][r*40+p*8] = bV[half];
          }
        }
      }
      // epilogue: sums3 + per-(b,s) min/max over the 64 rows of each group
#pragma unroll
      for (int nt=0; nt<4; ++nt){
        float s=0.f, s2=0.f, mx=-3.0e38f, mn=3.0e38f;
#pragma unroll
        for (int mt=0; mt<4; ++mt)
#pragma unroll
          for (int r=0; r<4; ++r){
            float v=acc[mt][nt][r];
            s+=v; s2=fmaf(v,v,s2);
            mx=fmaxf(mx,v); mn=fminf(mn,v);
          }
        s  += __shfl_xor(s,16,64);  s  += __shfl_xor(s,32,64);
        s2 += __shfl_xor(s2,16,64); s2 += __shfl_xor(s2,32,64);
        mx = fmaxf(mx, __shfl_xor(mx,16,64)); mx = fmaxf(mx, __shfl_xor(mx,32,64));
        mn = fminf(mn, __shfl_xor(mn,16,64)); mn = fminf(mn, __shfl_xor(mn,32,64));
        if (lane<16){
          int c = h*128 + wn*64+nt*16+lane;
          atomicAdd(&slots[(slot*256+c)*2+0], s);
          atomicAdd(&slots[(slot*256+c)*2+1], s2);
          size_t sidx = (size_t)mblk*2 + wm;         // global (b*1024+s)
          maxv[sidx*256 + c] = mx;
          minv[sidx*256 + c] = mn;
        }
      }
    }
  }
}

// ---------------------------------------------------------------------------
// Reduce 64 partial-sum slots -> per-channel scale/shift
// ---------------------------------------------------------------------------
__global__ void stats_kernel(const float* __restrict__ slots, const float* __restrict__ g,
                             const float* __restrict__ beta, float* __restrict__ ssOut,
                             int C, float inv_cnt){
  int c = threadIdx.x;
  if (c >= C) return;
  float s=0.f, s2=0.f;
  for (int k=0;k<64;++k){
    s  += slots[(k*C + c)*2 + 0];
    s2 += slots[(k*C + c)*2 + 1];
  }
  float m = s * inv_cnt;
  float v = fmaxf(s2 * inv_cnt - m*m, 0.f);
  float sc = rsqrtf(v + 1e-5f) * g[c];
  ssOut[c] = sc;
  ssOut[C + c] = beta[c] - m*sc;
}

// ---------------------------------------------------------------------------
// BN3 affine + relu on per-group max (min if scale<0); LDS-transposed so both
// the min/max reads and the (b,c,s)-layout writes are coalesced.
// ---------------------------------------------------------------------------
__global__ __launch_bounds__(256) void final_kernel(const float* __restrict__ minv,
                                                    const float* __restrict__ maxv,
                                                    const float* __restrict__ ss3,
                                                    float* __restrict__ out){
  __shared__ float tile[64][65];
  const int t = threadIdx.x;
  const int cb = blockIdx.x;   // 0..3  (64-channel block)
  const int sb = blockIdx.y;   // 0..15 (64-sample block)
  const int b  = blockIdx.z;   // 0..7
  const int w = t>>6, l = t&63;
  {
    int c = cb*64 + l;
    float sc = ss3[c], sh = ss3[256+c];
#pragma unroll
    for (int k=0;k<16;++k){
      int sl = k*4 + w;
      size_t mi = ((size_t)(b*1024 + sb*64 + sl))*256 + c;
      float v = (sc >= 0.f) ? maxv[mi] : minv[mi];
      tile[sl][l] = fmaxf(fmaf(v, sc, sh), 0.f);
    }
  }
  __syncthreads();
#pragma unroll
  for (int k=0;k<16;++k){
    int cl = k*4 + w;
    out[((size_t)(b*256 + cb*64 + cl))*1024 + sb*64 + l] = tile[l][cl];
  }
}

// ---------------------------------------------------------------------------
extern "C" void kernel_launch(void* const* d_in, const int* in_sizes, int n_in,
                              void* d_out, int out_size, void* d_ws, size_t ws_size,
                              hipStream_t stream){
  const float* xyz      = (const float*)d_in[0];
  const float* features = (const float*)d_in[1];
  const float* W1 = (const float*)d_in[2];
  const float* g1 = (const float*)d_in[3];
  const float* b1 = (const float*)d_in[4];
  const float* W2 = (const float*)d_in[5];
  const float* g2 = (const float*)d_in[6];
  const float* b2 = (const float*)d_in[7];
  const float* W3 = (const float*)d_in[8];
  const float* g3 = (const float*)d_in[9];
  const float* b3 = (const float*)d_in[10];
  float* out = (float*)d_out;

  char* ws = (char*)d_ws;
  size_t off = 0;
  auto alloc = [&](size_t bytes)->char*{
    char* p = ws + off;
    off = (off + bytes + 255) & ~(size_t)255;
    return p;
  };
  // total ~28 MB
  float* slots1 = (float*)alloc((size_t)64*128*2*4);
  float* slots2 = (float*)alloc((size_t)64*128*2*4);
  float* slots3 = (float*)alloc((size_t)64*256*2*4);
  float* ss1    = (float*)alloc(256*4);
  float* ss2    = (float*)alloc(256*4);
  float* ss3    = (float*)alloc(512*4);
  float* nxyz   = (float*)alloc((size_t)24576*4);
  int*   gi     = (int*)  alloc((size_t)M_*4);
  unsigned short* featT = (unsigned short*)alloc((size_t)B_*N_*CF_*2);
  unsigned short* Wt1   = (unsigned short*)alloc((size_t)128*160*2);
  unsigned short* Wt2   = (unsigned short*)alloc((size_t)128*128*2);
  unsigned short* Wt3   = (unsigned short*)alloc((size_t)256*128*2);
  float* minv = (float*)alloc((size_t)B_*S_*256*4);
  float* maxv = (float*)alloc((size_t)B_*S_*256*4);

  // zero the contiguous atomic-accumulator slots (256 KiB)
  hipMemsetAsync(slots1, 0, (size_t)(64*128*2 + 64*128*2 + 64*256*2)*4, stream);

  transpose_kernel<<<dim3(128,4,8), 256, 0, stream>>>(features, featT);
  wprep_kernel<<<64, 256, 0, stream>>>(W1, W2, W3, Wt1, Wt2, Wt3);
  fps_kernel<<<8, 256, 0, stream>>>(xyz, out, nxyz);
  qbp_kernel<<<2048, 256, 0, stream>>>(xyz, nxyz, gi);

  const float inv_cnt = 1.0f / (float)M_;
  mm_fused<1><<<4096, 256, 0, stream>>>(featT, Wt1, Wt2, Wt3, gi, xyz, nxyz,
                                        nullptr, nullptr, slots1, nullptr, nullptr);
  stats_kernel<<<1, 128, 0, stream>>>(slots1, g1, b1, ss1, 128, inv_cnt);
  mm_fused<2><<<4096, 256, 0, stream>>>(featT, Wt1, Wt2, Wt3, gi, xyz, nxyz,
                                        ss1, nullptr, slots2, nullptr, nullptr);
  stats_kernel<<<1, 128, 0, stream>>>(slots2, g2, b2, ss2, 128, inv_cnt);
  mm_fused<3><<<4096, 256, 0, stream>>>(featT, Wt1, Wt2, Wt3, gi, xyz, nxyz,
                                        ss1, ss2, slots3, minv, maxv);
  stats_kernel<<<1, 256, 0, stream>>>(slots3, g3, b3, ss3, 256, inv_cnt);
  final_kernel<<<dim3(4,16,8), 256, 0, stream>>>(minv, maxv, ss3, out + 24576);
}

// Round 10
// 1144.448 us; speedup vs baseline: 1.1721x; 1.1721x over previous
//
#include <hip/hip_runtime.h>

#define B_  8
#define N_  4096
#define S_  1024
#define K_  64
#define CF_ 128
#define M_  (B_*S_*K_)   // 524288 rows per layer

typedef __attribute__((ext_vector_type(8))) short bshort8;
typedef __attribute__((ext_vector_type(4))) float f32x4;
typedef __attribute__((ext_vector_type(4))) int   i32x4;
typedef __attribute__((ext_vector_type(2))) float f32x2;
typedef __attribute__((ext_vector_type(4))) unsigned short us4;

__device__ __forceinline__ unsigned short f2bf(float f){
  unsigned int u = __float_as_uint(f);
  u = u + 0x7FFFu + ((u >> 16) & 1u);      // RTNE
  return (unsigned short)(u >> 16);
}
__device__ __forceinline__ float bf2f(unsigned short h){
  return __uint_as_float(((unsigned int)h) << 16);
}

// ---------------------------------------------------------------------------
// FPS: EXACT r7 version (best measured: 785us). Serial-chain attacks v5/v6
// both regressed -> this structure is the measured floor. DO NOT TOUCH.
// ---------------------------------------------------------------------------
#define DPP_PAIR_STEP(CTRL)                                                     \
  {                                                                             \
    int _vi = __builtin_amdgcn_update_dpp(__float_as_int(best), __float_as_int(best), (CTRL), 0xF, 0xF, false); \
    int _ii = __builtin_amdgcn_update_dpp(bidx, bidx, (CTRL), 0xF, 0xF, false); \
    float _ov = __int_as_float(_vi);                                            \
    bool _tk = (_ov > best) || (_ov == best && _ii < bidx);                     \
    best = _tk ? _ov : best;                                                    \
    bidx = _tk ? _ii : bidx;                                                    \
  }

__global__ __launch_bounds__(256) void fps_kernel(const float* __restrict__ xyz,
                                                  float* __restrict__ nx_out,
                                                  float* __restrict__ nx_ws){
#pragma clang fp contract(off)
  __shared__ float sx[N_], sy[N_], sz[N_];
  __shared__ int   sidx[S_];
  __shared__ alignas(16) float redv[2][4];
  __shared__ alignas(16) int   redi[2][4];
  const int b = blockIdx.x, t = threadIdx.x;
  const int lane = t & 63, w = t >> 6;      // 4 waves
  const float* xb = xyz + (size_t)b*N_*3;
  f32x2 px[8], py[8], pz[8], dist[8];
#pragma unroll
  for (int j=0;j<8;++j){
    int i0 = (2*j)*256 + t, i1 = (2*j+1)*256 + t;
    float x0=xb[i0*3+0], y0=xb[i0*3+1], z0=xb[i0*3+2];
    float x1=xb[i1*3+0], y1=xb[i1*3+1], z1=xb[i1*3+2];
    px[j] = (f32x2){x0,x1}; py[j] = (f32x2){y0,y1}; pz[j] = (f32x2){z0,z1};
    dist[j] = (f32x2){1e10f,1e10f};
    sx[i0]=x0; sy[i0]=y0; sz[i0]=z0;
    sx[i1]=x1; sy[i1]=y1; sz[i1]=z1;
  }
  __syncthreads();
  int farthest = 0;
  for (int it=0; it<S_; ++it){
    if (t==0) sidx[it] = farthest;
    float cx = sx[farthest], cy = sy[farthest], cz = sz[farthest];
    f32x2 cx2 = (f32x2){cx,cx}, cy2 = (f32x2){cy,cy}, cz2 = (f32x2){cz,cz};
    float best = -1.0f; int bidx = 0;
#pragma unroll
    for (int j=0;j<8;++j){
      f32x2 dx = px[j] - cx2;
      f32x2 dy = py[j] - cy2;
      f32x2 dz = pz[j] - cz2;
      f32x2 d  = (dx*dx + dy*dy) + dz*dz;
      f32x2 nd;
      nd.x = fminf(dist[j].x, d.x);
      nd.y = fminf(dist[j].y, d.y);
      dist[j] = nd;
      bool tk0 = nd.x > best;
      best = tk0 ? nd.x : best;
      bidx = tk0 ? ((2*j)*256 + t) : bidx;
      bool tk1 = nd.y > best;
      best = tk1 ? nd.y : best;
      bidx = tk1 ? ((2*j+1)*256 + t) : bidx;
    }
    DPP_PAIR_STEP(0xB1);   // quad_perm [1,0,3,2]  (xor 1)
    DPP_PAIR_STEP(0x4E);   // quad_perm [2,3,0,1]  (xor 2)
    DPP_PAIR_STEP(0x124);  // row_ror:4
    DPP_PAIR_STEP(0x128);  // row_ror:8
    DPP_PAIR_STEP(0x142);  // row_bcast:15
    DPP_PAIR_STEP(0x143);  // row_bcast:31
    const int buf = it & 1;
    if (lane == 63){ redv[buf][w] = best; redi[buf][w] = bidx; }
    __syncthreads();
    f32x4 vv = *(const f32x4*)&redv[buf][0];
    i32x4 iv = *(const i32x4*)&redi[buf][0];
    float v01 = vv[0]; int i01 = iv[0];
    { bool tk = (vv[1] > v01) || (vv[1] == v01 && iv[1] < i01); v01 = tk?vv[1]:v01; i01 = tk?iv[1]:i01; }
    float v23 = vv[2]; int i23 = iv[2];
    { bool tk = (vv[3] > v23) || (vv[3] == v23 && iv[3] < i23); v23 = tk?vv[3]:v23; i23 = tk?iv[3]:i23; }
    { bool tk = (v23 > v01) || (v23 == v01 && i23 < i01); v01 = tk?v23:v01; i01 = tk?i23:i01; }
    farthest = i01;
  }
  __syncthreads();
  for (int i=t; i<S_; i+=256){
    int id = sidx[i];
    size_t base = (size_t)(b*S_+i)*3;
    float vx=sx[id], vy=sy[id], vz=sz[id];
    nx_out[base+0]=vx; nx_out[base+1]=vy; nx_out[base+2]=vz;
    nx_ws[base+0]=vx;  nx_ws[base+1]=vy;  nx_ws[base+2]=vz;
  }
}

// ---------------------------------------------------------------------------
// Ball query: f64 membership (golden np ref is float64) — VERIFIED r4.
// ---------------------------------------------------------------------------
__global__ __launch_bounds__(256) void qbp_kernel(const float* __restrict__ xyz,
                                                  const float* __restrict__ nx,
                                                  int* __restrict__ gi){
  const double R2 = 0.2*0.2;
  int gtid = blockIdx.x*256 + threadIdx.x;
  int wid = gtid >> 6, lane = gtid & 63;
  int b = wid >> 10, s = wid & 1023;
  const float* xb = xyz + (size_t)b*N_*3;
  const float* c  = nx + (size_t)(b*S_+s)*3;
  double cx=(double)c[0], cy=(double)c[1], cz=(double)c[2];
  double cc = cx*cx + cy*cy + cz*cz;
  int* g = gi + (size_t)(b*S_+s)*K_;
  int count = 0, first = -1;
  for (int ch=0; ch<64 && count<K_; ++ch){
    int i = ch*64 + lane;
    double x = (double)xb[i*3+0], y = (double)xb[i*3+1], z = (double)xb[i*3+2];
    double e  = cx*x + cy*y + cz*z;
    double pp = x*x + y*y + z*z;
    double d  = -2.0*e + cc + pp;
    bool keep = !(d > R2);
    unsigned long long bal = __ballot(keep);
    int pos = count + __builtin_popcountll(bal & ((1ull<<lane)-1ull));
    if (keep && pos < K_) g[pos] = i;
    if (first < 0 && bal) first = ch*64 + (int)__builtin_ctzll(bal);
    count += __builtin_popcountll(bal);
  }
  if (count < K_){
    int p = count + lane;
    if (p < K_) g[p] = first;
  }
}

// ---------------------------------------------------------------------------
// features (B,128,4096) f32 -> featT (B,4096,128) bf16
// ---------------------------------------------------------------------------
__global__ __launch_bounds__(256) void transpose_kernel(const float* __restrict__ f,
                                                        unsigned short* __restrict__ ft){
  __shared__ float tile[32][33];
  int b = blockIdx.z, ct = blockIdx.y, nt = blockIdx.x;
  int tx = threadIdx.x & 31, ty = threadIdx.x >> 5;
#pragma unroll
  for (int r=0; r<32; r+=8)
    tile[ty+r][tx] = f[((size_t)(b*128 + ct*32 + ty + r))*4096 + nt*32 + tx];
  __syncthreads();
#pragma unroll
  for (int r=0; r<32; r+=8){
    int n = nt*32 + ty + r, cc = ct*32 + tx;
    ft[((size_t)b*4096 + n)*128 + cc] = f2bf(tile[tx][ty+r]);
  }
}

// ---------------------------------------------------------------------------
// Weights -> bf16 [n][k]; layer-1 K permuted to [feat(0..127), dxyz, pad]
// ---------------------------------------------------------------------------
__global__ void wprep_kernel(const float* __restrict__ W1, const float* __restrict__ W2,
                             const float* __restrict__ W3,
                             unsigned short* __restrict__ Wt1, unsigned short* __restrict__ Wt2,
                             unsigned short* __restrict__ Wt3){
  int t = blockIdx.x*blockDim.x + threadIdx.x;
  int stride = gridDim.x*blockDim.x;
  for (int idx=t; idx<128*160; idx+=stride){
    int n = idx/160, k = idx-(idx/160)*160;
    float v = 0.f;
    if (k < 128) v = W1[(k+3)*128 + n];
    else if (k < 131) v = W1[(k-128)*128 + n];
    Wt1[idx] = f2bf(v);
  }
  for (int idx=t; idx<128*128; idx+=stride){
    int n = idx>>7, k = idx&127;
    Wt2[idx] = f2bf(W2[k*128+n]);
  }
  for (int idx=t; idx<256*128; idx+=stride){
    int n = idx>>7, k = idx&127;
    Wt3[idx] = f2bf(W3[k*256+n]);
  }
}

// ---------------------------------------------------------------------------
// P = featT(bf16) x W1_feat(bf16) -> f32 [B*N][128]. 1.3 GF, run once.
// Same MFMA fragment scheme as mm_fused; no gather (rows sequential).
// ---------------------------------------------------------------------------
__global__ __launch_bounds__(256,2) void pgemm_kernel(const unsigned short* __restrict__ featT,
                                                      const unsigned short* __restrict__ Wt1,
                                                      float* __restrict__ P){
  __shared__ alignas(16) unsigned short At[128*40];
  __shared__ alignas(16) unsigned short Bt[128*40];
  const int t = threadIdx.x, blk = blockIdx.x;     // 256 blocks
  const size_t rowBase = (size_t)blk*128;
  const int lane = t&63, wave = t>>6;
  const int wm = wave>>1, wn = wave&1;
  const int lrow = lane&15, quad = lane>>4;
  f32x4 acc[4][4];
  const f32x4 z4 = {0.f,0.f,0.f,0.f};
#pragma unroll
  for (int i=0;i<4;++i)
#pragma unroll
    for (int j=0;j<4;++j) acc[i][j]=z4;
  for (int ch=0; ch<4; ++ch){
    __syncthreads();
#pragma unroll
    for (int half=0; half<2; ++half){
      int sl = t + half*256; int r = sl>>2, p = sl&3;
      *(bshort8*)&At[r*40+p*8] = *(const bshort8*)(featT + (rowBase + r)*CF_ + ch*32 + p*8);
      *(bshort8*)&Bt[r*40+p*8] = *(const bshort8*)(Wt1 + r*160 + ch*32 + p*8);
    }
    __syncthreads();
    bshort8 af[4], bfr[4];
#pragma unroll
    for (int mt=0; mt<4; ++mt) af[mt]  = *(const bshort8*)&At[(wm*64+mt*16+lrow)*40 + quad*8];
#pragma unroll
    for (int nt=0; nt<4; ++nt) bfr[nt] = *(const bshort8*)&Bt[(wn*64+nt*16+lrow)*40 + quad*8];
#pragma unroll
    for (int mt=0; mt<4; ++mt)
#pragma unroll
      for (int nt=0; nt<4; ++nt)
        acc[mt][nt] = __builtin_amdgcn_mfma_f32_16x16x32_bf16(af[mt], bfr[nt], acc[mt][nt], 0,0,0);
  }
#pragma unroll
  for (int mt=0; mt<4; ++mt)
#pragma unroll
    for (int nt=0; nt<4; ++nt)
#pragma unroll
      for (int r=0; r<4; ++r){
        int row = wm*64 + mt*16 + quad*4 + r;
        int col = wn*64 + nt*16 + lrow;
        P[(rowBase + row)*128 + col] = acc[mt][nt][r];
      }
}

// ---------------------------------------------------------------------------
// Fused chain per 128-row slab, v3: GEMM1 replaced by P-row gather + f32
// dxyz affine (y1 = P[gi] + dxyz*W1_xyz).
// PHASE 1: y1 stats only (no MFMA)
// PHASE 2: z1(Y) -> GEMM2 (dbuf) -> col sums2
// PHASE 3: z1(Y) -> GEMM2 -> BN2 -> GEMM3 (2 halves) -> sums3+min/max
// ---------------------------------------------------------------------------
template<int PHASE>
__global__ __launch_bounds__(256,2) void mm_fused(
    const float* __restrict__ P,
    const float* __restrict__ W1,
    const unsigned short* __restrict__ Wt2,
    const unsigned short* __restrict__ Wt3,
    const int* __restrict__ gi,
    const float* __restrict__ xyz,
    const float* __restrict__ nxyz,
    const float* __restrict__ ss1,
    const float* __restrict__ ss2,
    float* __restrict__ slots,
    float* __restrict__ minv,
    float* __restrict__ maxv)
{
  __shared__ alignas(16) unsigned short Bt[2][(PHASE>=2)?(128*40):8];
  __shared__ alignas(16) unsigned short Y[(PHASE>=2)?(128*136):16];
  __shared__ int giL[128];
  __shared__ alignas(16) float dxL[128][4];
  __shared__ alignas(16) float w0L[128], w1L[128], w2L[128];
  __shared__ float sLDS[(PHASE==1)?128:4], s2LDS[(PHASE==1)?128:4];

  const int t = threadIdx.x;
  const int mblk = blockIdx.x;
  const int b = mblk >> 9;                 // 512 slabs per batch
  const int lane = t&63, wave = t>>6;
  const int wm = wave>>1, wn = wave&1;
  const int lrow = lane&15, quad = lane>>4;
  const int slot = mblk & 63;

  if (t<128){
    int i = gi[(size_t)mblk*128 + t];
    giL[t] = i;
    int s = ((mblk*128 + t) >> 6) & 1023;
    const float* pp = xyz  + ((size_t)b*N_ + i)*3;
    const float* qq = nxyz + (size_t)(b*S_ + s)*3;
    dxL[t][0] = __fsub_rn(pp[0],qq[0]);
    dxL[t][1] = __fsub_rn(pp[1],qq[1]);
    dxL[t][2] = __fsub_rn(pp[2],qq[2]);
    w0L[t] = W1[t]; w1L[t] = W1[128+t]; w2L[t] = W1[256+t];
    if constexpr (PHASE==1){ sLDS[t]=0.f; s2LDS[t]=0.f; }
  }
  __syncthreads();

  // ---- y1 pass: 8 rows in flight, 32 threads/row (one f32x4 per thread) ----
  {
    const int rgrp = t>>5, cq = (t&31)*4;
    f32x4 w0 = *(const f32x4*)&w0L[cq];
    f32x4 w1 = *(const f32x4*)&w1L[cq];
    f32x4 w2 = *(const f32x4*)&w2L[cq];
    f32x4 a1v, b1v;
    if constexpr (PHASE>=2){
      a1v = *(const f32x4*)(ss1 + cq);
      b1v = *(const f32x4*)(ss1 + 128 + cq);
    }
    f32x4 sA = {0,0,0,0}, s2A = {0,0,0,0};
#pragma unroll
    for (int g=0; g<16; ++g){
      int r = g*8 + rgrp;
      int pi = giL[r];
      f32x4 p = *(const f32x4*)(P + ((size_t)b*N_ + pi)*128 + cq);
      float dx = dxL[r][0], dy = dxL[r][1], dz = dxL[r][2];
      f32x4 y;
#pragma unroll
      for (int e=0;e<4;++e)
        y[e] = fmaf(dz, w2[e], fmaf(dy, w1[e], fmaf(dx, w0[e], p[e])));
      if constexpr (PHASE==1){
#pragma unroll
        for (int e=0;e<4;++e){ sA[e] += y[e]; s2A[e] = fmaf(y[e], y[e], s2A[e]); }
      } else {
        us4 zz;
#pragma unroll
        for (int e=0;e<4;++e)
          zz[e] = f2bf(fmaxf(fmaf(y[e], a1v[e], b1v[e]), 0.f));
        *(us4*)&Y[r*136 + cq] = zz;
      }
    }
    if constexpr (PHASE==1){
#pragma unroll
      for (int e=0;e<4;++e){
        atomicAdd(&sLDS[cq+e],  sA[e]);
        atomicAdd(&s2LDS[cq+e], s2A[e]);
      }
      __syncthreads();
      if (t<128){
        atomicAdd(&slots[(slot*128+t)*2+0], sLDS[t]);
        atomicAdd(&slots[(slot*128+t)*2+1], s2LDS[t]);
      }
      return;
    }
  }

  if constexpr (PHASE>=2){
    f32x4 acc[4][4];
    const f32x4 z4 = {0.f,0.f,0.f,0.f};
#pragma unroll
    for (int i=0;i<4;++i)
#pragma unroll
      for (int j=0;j<4;++j) acc[i][j]=z4;

    // ---------------- GEMM2 (dbuf): A = Y (z1), K=128 ----------------
    {
      bshort8 bV[2];
#pragma unroll
      for (int half=0; half<2; ++half){
        int sl = t + half*256; int r = sl>>2, p = sl&3;
        bV[half] = *(const bshort8*)(Wt2 + r*128 + p*8);
      }
#pragma unroll
      for (int half=0; half<2; ++half){
        int sl = t + half*256; int r = sl>>2, p = sl&3;
        *(bshort8*)&Bt[1][r*40+p*8] = bV[half];
      }
      for (int ch=0; ch<4; ++ch){
        const int cur = (ch & 1) ^ 1;
        __syncthreads();   // covers Y staging (first iter) + Bt[cur]
        bshort8 af[4], bfr[4];
#pragma unroll
        for (int mt=0; mt<4; ++mt) af[mt]  = *(const bshort8*)&Y[(wm*64+mt*16+lrow)*136 + ch*32 + quad*8];
#pragma unroll
        for (int nt=0; nt<4; ++nt) bfr[nt] = *(const bshort8*)&Bt[cur][(wn*64+nt*16+lrow)*40 + quad*8];
        if (ch < 3){
#pragma unroll
          for (int half=0; half<2; ++half){
            int sl = t + half*256; int r = sl>>2, p = sl&3;
            bV[half] = *(const bshort8*)(Wt2 + r*128 + (ch+1)*32 + p*8);
          }
        }
#pragma unroll
        for (int mt=0; mt<4; ++mt)
#pragma unroll
          for (int nt=0; nt<4; ++nt)
            acc[mt][nt] = __builtin_amdgcn_mfma_f32_16x16x32_bf16(af[mt], bfr[nt], acc[mt][nt], 0,0,0);
        if (ch < 3){
          const int nxt = cur ^ 1;
#pragma unroll
          for (int half=0; half<2; ++half){
            int sl = t + half*256; int r = sl>>2, p = sl&3;
            *(bshort8*)&Bt[nxt][r*40+p*8] = bV[half];
          }
        }
      }
    }

    if constexpr (PHASE==2){
#pragma unroll
      for (int nt=0; nt<4; ++nt){
        float s=0.f, s2=0.f;
#pragma unroll
        for (int mt=0; mt<4; ++mt)
#pragma unroll
          for (int r=0; r<4; ++r){ float v=acc[mt][nt][r]; s+=v; s2=fmaf(v,v,s2); }
        s  += __shfl_xor(s,16,64);  s  += __shfl_xor(s,32,64);
        s2 += __shfl_xor(s2,16,64); s2 += __shfl_xor(s2,32,64);
        if (lane<16){
          int c = wn*64+nt*16+lane;
          atomicAdd(&slots[(slot*128+c)*2+0], s);
          atomicAdd(&slots[(slot*128+c)*2+1], s2);
        }
      }
      return;
    }

    if constexpr (PHASE==3){
      // ---- BN2 + ReLU -> Y (overwrite); barrier for in-flight Y reads ----
      __syncthreads();
#pragma unroll
      for (int nt=0; nt<4; ++nt){
        int c = wn*64+nt*16+lrow;
        float sc = ss2[c], sh = ss2[128+c];
#pragma unroll
        for (int mt=0; mt<4; ++mt)
#pragma unroll
          for (int r=0; r<4; ++r){
            int row = wm*64+mt*16+quad*4+r;
            Y[row*136 + c] = f2bf(fmaxf(fmaf(acc[mt][nt][r], sc, sh), 0.f));
          }
      }

      // ---------------- GEMM3 (dbuf): Nout=256 in two halves ----------------
      for (int h=0; h<2; ++h){
#pragma unroll
        for (int i=0;i<4;++i)
#pragma unroll
          for (int j=0;j<4;++j) acc[i][j]=z4;
        bshort8 bV[2];
#pragma unroll
        for (int half=0; half<2; ++half){
          int sl = t + half*256; int r = sl>>2, p = sl&3;
          bV[half] = *(const bshort8*)(Wt3 + ((size_t)(h*128+r))*128 + p*8);
        }
#pragma unroll
        for (int half=0; half<2; ++half){
          int sl = t + half*256; int r = sl>>2, p = sl&3;
          *(bshort8*)&Bt[1][r*40+p*8] = bV[half];
        }
        for (int ch=0; ch<4; ++ch){
          const int cur = (ch & 1) ^ 1;
          __syncthreads();
          bshort8 af[4], bfr[4];
#pragma unroll
          for (int mt=0; mt<4; ++mt) af[mt]  = *(const bshort8*)&Y[(wm*64+mt*16+lrow)*136 + ch*32 + quad*8];
#pragma unroll
          for (int nt=0; nt<4; ++nt) bfr[nt] = *(const bshort8*)&Bt[cur][(wn*64+nt*16+lrow)*40 + quad*8];
          if (ch < 3){
#pragma unroll
            for (int half=0; half<2; ++half){
              int sl = t + half*256; int r = sl>>2, p = sl&3;
              bV[half] = *(const bshort8*)(Wt3 + ((size_t)(h*128+r))*128 + (ch+1)*32 + p*8);
            }
          }
#pragma unroll
          for (int mt=0; mt<4; ++mt)
#pragma unroll
            for (int nt=0; nt<4; ++nt)
              acc[mt][nt] = __builtin_amdgcn_mfma_f32_16x16x32_bf16(af[mt], bfr[nt], acc[mt][nt], 0,0,0);
          if (ch < 3){
            const int nxt = cur ^ 1;
#pragma unroll
            for (int half=0; half<2; ++half){
              int sl = t + half*256; int r = sl>>2, p = sl&3;
              *(bshort8*)&Bt[nxt][r*40+p*8] = bV[half];
            }
          }
        }
        // epilogue: sums3 + per-(b,s) min/max over the 64 rows of each group
#pragma unroll
        for (int nt=0; nt<4; ++nt){
          float s=0.f, s2=0.f, mx=-3.0e38f, mn=3.0e38f;
#pragma unroll
          for (int mt=0; mt<4; ++mt)
#pragma unroll
            for (int r=0; r<4; ++r){
              float v=acc[mt][nt][r];
              s+=v; s2=fmaf(v,v,s2);
              mx=fmaxf(mx,v); mn=fminf(mn,v);
            }
          s  += __shfl_xor(s,16,64);  s  += __shfl_xor(s,32,64);
          s2 += __shfl_xor(s2,16,64); s2 += __shfl_xor(s2,32,64);
          mx = fmaxf(mx, __shfl_xor(mx,16,64)); mx = fmaxf(mx, __shfl_xor(mx,32,64));
          mn = fminf(mn, __shfl_xor(mn,16,64)); mn = fminf(mn, __shfl_xor(mn,32,64));
          if (lane<16){
            int c = h*128 + wn*64+nt*16+lane;
            atomicAdd(&slots[(slot*256+c)*2+0], s);
            atomicAdd(&slots[(slot*256+c)*2+1], s2);
            size_t sidx = (size_t)mblk*2 + wm;         // global (b*1024+s)
            maxv[sidx*256 + c] = mx;
            minv[sidx*256 + c] = mn;
          }
        }
      }
    }
  }
}

// ---------------------------------------------------------------------------
// Reduce 64 partial-sum slots -> per-channel scale/shift
// ---------------------------------------------------------------------------
__global__ void stats_kernel(const float* __restrict__ slots, const float* __restrict__ g,
                             const float* __restrict__ beta, float* __restrict__ ssOut,
                             int C, float inv_cnt){
  int c = threadIdx.x;
  if (c >= C) return;
  float s=0.f, s2=0.f;
  for (int k=0;k<64;++k){
    s  += slots[(k*C + c)*2 + 0];
    s2 += slots[(k*C + c)*2 + 1];
  }
  float m = s * inv_cnt;
  float v = fmaxf(s2 * inv_cnt - m*m, 0.f);
  float sc = rsqrtf(v + 1e-5f) * g[c];
  ssOut[c] = sc;
  ssOut[C + c] = beta[c] - m*sc;
}

// ---------------------------------------------------------------------------
// BN3 affine + relu on per-group max (min if scale<0); LDS-transposed.
// ---------------------------------------------------------------------------
__global__ __launch_bounds__(256) void final_kernel(const float* __restrict__ minv,
                                                    const float* __restrict__ maxv,
                                                    const float* __restrict__ ss3,
                                                    float* __restrict__ out){
  __shared__ float tile[64][65];
  const int t = threadIdx.x;
  const int cb = blockIdx.x;
  const int sb = blockIdx.y;
  const int b  = blockIdx.z;
  const int w = t>>6, l = t&63;
  {
    int c = cb*64 + l;
    float sc = ss3[c], sh = ss3[256+c];
#pragma unroll
    for (int k=0;k<16;++k){
      int sl = k*4 + w;
      size_t mi = ((size_t)(b*1024 + sb*64 + sl))*256 + c;
      float v = (sc >= 0.f) ? maxv[mi] : minv[mi];
      tile[sl][l] = fmaxf(fmaf(v, sc, sh), 0.f);
    }
  }
  __syncthreads();
#pragma unroll
  for (int k=0;k<16;++k){
    int cl = k*4 + w;
    out[((size_t)(b*256 + cb*64 + cl))*1024 + sb*64 + l] = tile[l][cl];
  }
}

// ---------------------------------------------------------------------------
extern "C" void kernel_launch(void* const* d_in, const int* in_sizes, int n_in,
                              void* d_out, int out_size, void* d_ws, size_t ws_size,
                              hipStream_t stream){
  const float* xyz      = (const float*)d_in[0];
  const float* features = (const float*)d_in[1];
  const float* W1 = (const float*)d_in[2];
  const float* g1 = (const float*)d_in[3];
  const float* b1 = (const float*)d_in[4];
  const float* W2 = (const float*)d_in[5];
  const float* g2 = (const float*)d_in[6];
  const float* b2 = (const float*)d_in[7];
  const float* W3 = (const float*)d_in[8];
  const float* g3 = (const float*)d_in[9];
  const float* b3 = (const float*)d_in[10];
  float* out = (float*)d_out;

  char* ws = (char*)d_ws;
  size_t off = 0;
  auto alloc = [&](size_t bytes)->char*{
    char* p = ws + off;
    off = (off + bytes + 255) & ~(size_t)255;
    return p;
  };
  // total ~45 MB
  float* slots1 = (float*)alloc((size_t)64*128*2*4);
  float* slots2 = (float*)alloc((size_t)64*128*2*4);
  float* slots3 = (float*)alloc((size_t)64*256*2*4);
  float* ss1    = (float*)alloc(256*4);
  float* ss2    = (float*)alloc(256*4);
  float* ss3    = (float*)alloc(512*4);
  float* nxyz   = (float*)alloc((size_t)24576*4);
  int*   gi     = (int*)  alloc((size_t)M_*4);
  unsigned short* featT = (unsigned short*)alloc((size_t)B_*N_*CF_*2);
  unsigned short* Wt1   = (unsigned short*)alloc((size_t)128*160*2);
  unsigned short* Wt2   = (unsigned short*)alloc((size_t)128*128*2);
  unsigned short* Wt3   = (unsigned short*)alloc((size_t)256*128*2);
  float* minv = (float*)alloc((size_t)B_*S_*256*4);
  float* maxv = (float*)alloc((size_t)B_*S_*256*4);
  float* P    = (float*)alloc((size_t)B_*N_*128*4);   // 16.8 MB

  // zero the contiguous atomic-accumulator slots (256 KiB)
  hipMemsetAsync(slots1, 0, (size_t)(64*128*2 + 64*128*2 + 64*256*2)*4, stream);

  transpose_kernel<<<dim3(128,4,8), 256, 0, stream>>>(features, featT);
  wprep_kernel<<<64, 256, 0, stream>>>(W1, W2, W3, Wt1, Wt2, Wt3);
  pgemm_kernel<<<256, 256, 0, stream>>>(featT, Wt1, P);
  fps_kernel<<<8, 256, 0, stream>>>(xyz, out, nxyz);
  qbp_kernel<<<2048, 256, 0, stream>>>(xyz, nxyz, gi);

  const float inv_cnt = 1.0f / (float)M_;
  mm_fused<1><<<4096, 256, 0, stream>>>(P, W1, Wt2, Wt3, gi, xyz, nxyz,
                                        nullptr, nullptr, slots1, nullptr, nullptr);
  stats_kernel<<<1, 128, 0, stream>>>(slots1, g1, b1, ss1, 128, inv_cnt);
  mm_fused<2><<<4096, 256, 0, stream>>>(P, W1, Wt2, Wt3, gi, xyz, nxyz,
                                        ss1, nullptr, slots2, nullptr, nullptr);
  stats_kernel<<<1, 128, 0, stream>>>(slots2, g2, b2, ss2, 128, inv_cnt);
  mm_fused<3><<<4096, 256, 0, stream>>>(P, W1, Wt2, Wt3, gi, xyz, nxyz,
                                        ss1, ss2, slots3, minv, maxv);
  stats_kernel<<<1, 256, 0, stream>>>(slots3, g3, b3, ss3, 256, inv_cnt);
  final_kernel<<<dim3(4,16,8), 256, 0, stream>>>(minv, maxv, ss3, out + 24576);
}

// Round 11
// 1126.569 us; speedup vs baseline: 1.1907x; 1.0159x over previous
//
#include <hip/hip_runtime.h>

#define B_  8
#define N_  4096
#define S_  1024
#define K_  64
#define CF_ 128
#define M_  (B_*S_*K_)   // 524288 rows per layer

typedef __attribute__((ext_vector_type(8))) short bshort8;
typedef __attribute__((ext_vector_type(4))) float f32x4;
typedef __attribute__((ext_vector_type(4))) int   i32x4;
typedef __attribute__((ext_vector_type(2))) float f32x2;
typedef __attribute__((ext_vector_type(4))) unsigned short us4;

__device__ __forceinline__ unsigned short f2bf(float f){
  unsigned int u = __float_as_uint(f);
  u = u + 0x7FFFu + ((u >> 16) & 1u);      // RTNE
  return (unsigned short)(u >> 16);
}
__device__ __forceinline__ float bf2f(unsigned short h){
  return __uint_as_float(((unsigned int)h) << 16);
}

// ---------------------------------------------------------------------------
// prep: transpose (blocks 0..4095) + weight prep (blocks 4096..4159)
// ---------------------------------------------------------------------------
__global__ __launch_bounds__(256) void prep_kernel(const float* __restrict__ f,
                                                   const float* __restrict__ W1,
                                                   const float* __restrict__ W2,
                                                   const float* __restrict__ W3,
                                                   unsigned short* __restrict__ ft,
                                                   unsigned short* __restrict__ Wt1,
                                                   unsigned short* __restrict__ Wt2,
                                                   unsigned short* __restrict__ Wt3){
  __shared__ float tile[32][33];
  const int blk = blockIdx.x;
  if (blk < 4096){
    int nt = blk & 127, ct = (blk>>7)&3, b = blk>>9;
    int tx = threadIdx.x & 31, ty = threadIdx.x >> 5;
#pragma unroll
    for (int r=0; r<32; r+=8)
      tile[ty+r][tx] = f[((size_t)(b*128 + ct*32 + ty + r))*4096 + nt*32 + tx];
    __syncthreads();
#pragma unroll
    for (int r=0; r<32; r+=8){
      int n = nt*32 + ty + r, cc = ct*32 + tx;
      ft[((size_t)b*4096 + n)*128 + cc] = f2bf(tile[tx][ty+r]);
    }
  } else {
    int t = (blk-4096)*256 + threadIdx.x;
    int stride = 64*256;
    for (int idx=t; idx<128*160; idx+=stride){
      int n = idx/160, k = idx-(idx/160)*160;
      float v = 0.f;
      if (k < 128) v = W1[(k+3)*128 + n];
      else if (k < 131) v = W1[(k-128)*128 + n];
      Wt1[idx] = f2bf(v);
    }
    for (int idx=t; idx<128*128; idx+=stride){
      int n = idx>>7, k = idx&127;
      Wt2[idx] = f2bf(W2[k*128+n]);
    }
    for (int idx=t; idx<256*128; idx+=stride){
      int n = idx>>7, k = idx&127;
      Wt3[idx] = f2bf(W3[k*256+n]);
    }
  }
}

// ---------------------------------------------------------------------------
// fps (blocks 0..7, EXACT r7 math/structure — measured floor 785us) in the
// same dispatch as pgemm (blocks 8..263, P = featT x W1_feat, independent of
// fps -> hidden under fps's 784us). LDS overlaid via char array.
// ---------------------------------------------------------------------------
#define DPP_PAIR_STEP(CTRL)                                                     \
  {                                                                             \
    int _vi = __builtin_amdgcn_update_dpp(__float_as_int(best), __float_as_int(best), (CTRL), 0xF, 0xF, false); \
    int _ii = __builtin_amdgcn_update_dpp(bidx, bidx, (CTRL), 0xF, 0xF, false); \
    float _ov = __int_as_float(_vi);                                            \
    bool _tk = (_ov > best) || (_ov == best && _ii < bidx);                     \
    best = _tk ? _ov : best;                                                    \
    bidx = _tk ? _ii : bidx;                                                    \
  }

__global__ __launch_bounds__(256) void fps_pgemm_kernel(const float* __restrict__ xyz,
                                                        float* __restrict__ nx_out,
                                                        float* __restrict__ nx_ws,
                                                        const unsigned short* __restrict__ featT,
                                                        const unsigned short* __restrict__ Wt1,
                                                        float* __restrict__ P){
#pragma clang fp contract(off)
  __shared__ alignas(16) char smem[53312];
  const int t = threadIdx.x;
  if (blockIdx.x < 8){
    // ---------------- FPS (r7, frozen) ----------------
    float* sx = (float*)smem;                       // [4096]
    float* sy = (float*)(smem+16384);
    float* sz = (float*)(smem+32768);
    int*   sidx = (int*)(smem+49152);               // [1024]
    float (*redv)[4] = (float(*)[4])(smem+53248);   // [2][4]
    int   (*redi)[4] = (int(*)[4])(smem+53280);
    const int b = blockIdx.x;
    const int lane = t & 63, w = t >> 6;
    const float* xb = xyz + (size_t)b*N_*3;
    f32x2 px[8], py[8], pz[8], dist[8];
#pragma unroll
    for (int j=0;j<8;++j){
      int i0 = (2*j)*256 + t, i1 = (2*j+1)*256 + t;
      float x0=xb[i0*3+0], y0=xb[i0*3+1], z0=xb[i0*3+2];
      float x1=xb[i1*3+0], y1=xb[i1*3+1], z1=xb[i1*3+2];
      px[j] = (f32x2){x0,x1}; py[j] = (f32x2){y0,y1}; pz[j] = (f32x2){z0,z1};
      dist[j] = (f32x2){1e10f,1e10f};
      sx[i0]=x0; sy[i0]=y0; sz[i0]=z0;
      sx[i1]=x1; sy[i1]=y1; sz[i1]=z1;
    }
    __syncthreads();
    int farthest = 0;
    for (int it=0; it<S_; ++it){
      if (t==0) sidx[it] = farthest;
      float cx = sx[farthest], cy = sy[farthest], cz = sz[farthest];
      f32x2 cx2 = (f32x2){cx,cx}, cy2 = (f32x2){cy,cy}, cz2 = (f32x2){cz,cz};
      float best = -1.0f; int bidx = 0;
#pragma unroll
      for (int j=0;j<8;++j){
        f32x2 dx = px[j] - cx2;
        f32x2 dy = py[j] - cy2;
        f32x2 dz = pz[j] - cz2;
        f32x2 d  = (dx*dx + dy*dy) + dz*dz;
        f32x2 nd;
        nd.x = fminf(dist[j].x, d.x);
        nd.y = fminf(dist[j].y, d.y);
        dist[j] = nd;
        bool tk0 = nd.x > best;
        best = tk0 ? nd.x : best;
        bidx = tk0 ? ((2*j)*256 + t) : bidx;
        bool tk1 = nd.y > best;
        best = tk1 ? nd.y : best;
        bidx = tk1 ? ((2*j+1)*256 + t) : bidx;
      }
      DPP_PAIR_STEP(0xB1);
      DPP_PAIR_STEP(0x4E);
      DPP_PAIR_STEP(0x124);
      DPP_PAIR_STEP(0x128);
      DPP_PAIR_STEP(0x142);
      DPP_PAIR_STEP(0x143);
      const int buf = it & 1;
      if (lane == 63){ redv[buf][w] = best; redi[buf][w] = bidx; }
      __syncthreads();
      f32x4 vv = *(const f32x4*)&redv[buf][0];
      i32x4 iv = *(const i32x4*)&redi[buf][0];
      float v01 = vv[0]; int i01 = iv[0];
      { bool tk = (vv[1] > v01) || (vv[1] == v01 && iv[1] < i01); v01 = tk?vv[1]:v01; i01 = tk?iv[1]:i01; }
      float v23 = vv[2]; int i23 = iv[2];
      { bool tk = (vv[3] > v23) || (vv[3] == v23 && iv[3] < i23); v23 = tk?vv[3]:v23; i23 = tk?iv[3]:i23; }
      { bool tk = (v23 > v01) || (v23 == v01 && i23 < i01); v01 = tk?v23:v01; i01 = tk?i23:i01; }
      farthest = i01;
    }
    __syncthreads();
    for (int i=t; i<S_; i+=256){
      int id = sidx[i];
      size_t base = (size_t)(b*S_+i)*3;
      float vx=sx[id], vy=sy[id], vz=sz[id];
      nx_out[base+0]=vx; nx_out[base+1]=vy; nx_out[base+2]=vz;
      nx_ws[base+0]=vx;  nx_ws[base+1]=vy;  nx_ws[base+2]=vz;
    }
  } else {
    // ---------------- pgemm: P = featT x W1_feat (f32 out) ----------------
    unsigned short* At = (unsigned short*)smem;            // 128*40
    unsigned short* Bt = (unsigned short*)(smem+10240);    // 128*40
    const int blk = blockIdx.x - 8;                        // 256 blocks
    const size_t rowBase = (size_t)blk*128;
    const int lane = t&63, wave = t>>6;
    const int wm = wave>>1, wn = wave&1;
    const int lrow = lane&15, quad = lane>>4;
    f32x4 acc[4][4];
    const f32x4 z4 = {0.f,0.f,0.f,0.f};
#pragma unroll
    for (int i=0;i<4;++i)
#pragma unroll
      for (int j=0;j<4;++j) acc[i][j]=z4;
    for (int ch=0; ch<4; ++ch){
      __syncthreads();
#pragma unroll
      for (int half=0; half<2; ++half){
        int sl = t + half*256; int r = sl>>2, p = sl&3;
        *(bshort8*)&At[r*40+p*8] = *(const bshort8*)(featT + (rowBase + r)*CF_ + ch*32 + p*8);
        *(bshort8*)&Bt[r*40+p*8] = *(const bshort8*)(Wt1 + r*160 + ch*32 + p*8);
      }
      __syncthreads();
      bshort8 af[4], bfr[4];
#pragma unroll
      for (int mt=0; mt<4; ++mt) af[mt]  = *(const bshort8*)&At[(wm*64+mt*16+lrow)*40 + quad*8];
#pragma unroll
      for (int nt=0; nt<4; ++nt) bfr[nt] = *(const bshort8*)&Bt[(wn*64+nt*16+lrow)*40 + quad*8];
#pragma unroll
      for (int mt=0; mt<4; ++mt)
#pragma unroll
        for (int nt=0; nt<4; ++nt)
          acc[mt][nt] = __builtin_amdgcn_mfma_f32_16x16x32_bf16(af[mt], bfr[nt], acc[mt][nt], 0,0,0);
    }
#pragma unroll
    for (int mt=0; mt<4; ++mt)
#pragma unroll
      for (int nt=0; nt<4; ++nt)
#pragma unroll
        for (int r=0; r<4; ++r){
          int row = wm*64 + mt*16 + quad*4 + r;
          int col = wn*64 + nt*16 + lrow;
          P[(rowBase + row)*128 + col] = acc[mt][nt][r];
        }
  }
}

// ---------------------------------------------------------------------------
// qbp + y1 column stats fused: each wave computes its query's ball indices
// (f64 membership — VERIFIED r4), writes them to global gi AND keeps them in
// LDS, then immediately accumulates y1 = P[gi] + dxyz*W1_xyz column sums for
// its 64 rows (2 cols/lane). Block-level LDS reduce -> 128 global atomics.
// ---------------------------------------------------------------------------
__global__ __launch_bounds__(256) void qbp_y1_kernel(const float* __restrict__ xyz,
                                                     const float* __restrict__ nx,
                                                     const float* __restrict__ P,
                                                     const float* __restrict__ W1,
                                                     int* __restrict__ gi,
                                                     float* __restrict__ slots){
  __shared__ int giW[4][64];
  __shared__ alignas(16) float dxL[4][64][4];
  __shared__ float sLDS[128], s2LDS[128];
  const int t = threadIdx.x;
  const int lane = t & 63, w = t >> 6;
  if (t < 128){ sLDS[t]=0.f; s2LDS[t]=0.f; }
  __syncthreads();
  const int wid = blockIdx.x*4 + w;
  const int b = wid >> 10, s = wid & 1023;
  const float* xb = xyz + (size_t)b*N_*3;
  {
    const double R2 = 0.2*0.2;
    const float* c  = nx + (size_t)(b*S_+s)*3;
    double cx=(double)c[0], cy=(double)c[1], cz=(double)c[2];
    double cc = cx*cx + cy*cy + cz*cz;
    int* g = gi + (size_t)(b*S_+s)*K_;
    int count = 0, first = -1;
    for (int ch=0; ch<64 && count<K_; ++ch){
      int i = ch*64 + lane;
      double x = (double)xb[i*3+0], y = (double)xb[i*3+1], z = (double)xb[i*3+2];
      double e  = cx*x + cy*y + cz*z;
      double pp = x*x + y*y + z*z;
      double d  = -2.0*e + cc + pp;
      bool keep = !(d > R2);
      unsigned long long bal = __ballot(keep);
      int pos = count + __builtin_popcountll(bal & ((1ull<<lane)-1ull));
      if (keep && pos < K_){ g[pos] = i; giW[w][pos] = i; }
      if (first < 0 && bal) first = ch*64 + (int)__builtin_ctzll(bal);
      count += __builtin_popcountll(bal);
    }
    if (count < K_){
      int p = count + lane;
      if (p < K_){ g[p] = first; giW[w][p] = first; }
    }
    // dxyz for row=lane (wave-local LDS, no barrier needed for own reads)
    int i = giW[w][lane];
    const float* pp = xyz + ((size_t)b*N_ + i)*3;
    const float* qq = nx  + (size_t)(b*S_ + s)*3;
    dxL[w][lane][0] = __fsub_rn(pp[0],qq[0]);
    dxL[w][lane][1] = __fsub_rn(pp[1],qq[1]);
    dxL[w][lane][2] = __fsub_rn(pp[2],qq[2]);
  }
  // ---- y1 stats: lane owns cols {2*lane, 2*lane+1} over its wave's 64 rows
  {
    const int cq = lane*2;
    f32x2 w0 = *(const f32x2*)(W1 + cq);
    f32x2 w1v = *(const f32x2*)(W1 + 128 + cq);
    f32x2 w2 = *(const f32x2*)(W1 + 256 + cq);
    f32x2 sA = {0,0}, s2A = {0,0};
#pragma unroll 4
    for (int r=0; r<64; ++r){
      int pi = giW[w][r];
      f32x2 p = *(const f32x2*)(P + ((size_t)b*N_ + pi)*128 + cq);
      float dx = dxL[w][r][0], dy = dxL[w][r][1], dz = dxL[w][r][2];
      f32x2 y;
#pragma unroll
      for (int e=0;e<2;++e)
        y[e] = fmaf(dz, w2[e], fmaf(dy, w1v[e], fmaf(dx, w0[e], p[e])));
      sA.x += y.x; sA.y += y.y;
      s2A.x = fmaf(y.x,y.x,s2A.x); s2A.y = fmaf(y.y,y.y,s2A.y);
    }
    atomicAdd(&sLDS[cq],    sA.x);  atomicAdd(&sLDS[cq+1],  sA.y);
    atomicAdd(&s2LDS[cq],   s2A.x); atomicAdd(&s2LDS[cq+1], s2A.y);
  }
  __syncthreads();
  if (t < 128){
    int slot = blockIdx.x & 63;
    atomicAdd(&slots[(slot*128+t)*2+0], sLDS[t]);
    atomicAdd(&slots[(slot*128+t)*2+1], s2LDS[t]);
  }
}

// ---------------------------------------------------------------------------
// Fused chain per 128-row slab (unchanged from passing r10):
// PHASE 2: y1 gather -> z1(Y) -> GEMM2 (dbuf) -> col sums2
// PHASE 3: y1 gather -> z1 -> GEMM2 -> BN2 -> GEMM3 (2 halves) -> sums3+min/max
// ---------------------------------------------------------------------------
template<int PHASE>
__global__ __launch_bounds__(256,2) void mm_fused(
    const float* __restrict__ P,
    const float* __restrict__ W1,
    const unsigned short* __restrict__ Wt2,
    const unsigned short* __restrict__ Wt3,
    const int* __restrict__ gi,
    const float* __restrict__ xyz,
    const float* __restrict__ nxyz,
    const float* __restrict__ ss1,
    const float* __restrict__ ss2,
    float* __restrict__ slots,
    float* __restrict__ minv,
    float* __restrict__ maxv)
{
  __shared__ alignas(16) unsigned short Bt[2][128*40];
  __shared__ alignas(16) unsigned short Y[128*136];
  __shared__ int giL[128];
  __shared__ alignas(16) float dxL[128][4];
  __shared__ alignas(16) float w0L[128], w1L[128], w2L[128];

  const int t = threadIdx.x;
  const int mblk = blockIdx.x;
  const int b = mblk >> 9;
  const int lane = t&63, wave = t>>6;
  const int wm = wave>>1, wn = wave&1;
  const int lrow = lane&15, quad = lane>>4;
  const int slot = mblk & 63;

  if (t<128){
    int i = gi[(size_t)mblk*128 + t];
    giL[t] = i;
    int s = ((mblk*128 + t) >> 6) & 1023;
    const float* pp = xyz  + ((size_t)b*N_ + i)*3;
    const float* qq = nxyz + (size_t)(b*S_ + s)*3;
    dxL[t][0] = __fsub_rn(pp[0],qq[0]);
    dxL[t][1] = __fsub_rn(pp[1],qq[1]);
    dxL[t][2] = __fsub_rn(pp[2],qq[2]);
    w0L[t] = W1[t]; w1L[t] = W1[128+t]; w2L[t] = W1[256+t];
  }
  __syncthreads();

  // ---- y1 + BN1 + ReLU -> Y: 8 rows in flight, 32 threads/row ----
  {
    const int rgrp = t>>5, cq = (t&31)*4;
    f32x4 w0 = *(const f32x4*)&w0L[cq];
    f32x4 w1 = *(const f32x4*)&w1L[cq];
    f32x4 w2 = *(const f32x4*)&w2L[cq];
    f32x4 a1v = *(const f32x4*)(ss1 + cq);
    f32x4 b1v = *(const f32x4*)(ss1 + 128 + cq);
#pragma unroll
    for (int g=0; g<16; ++g){
      int r = g*8 + rgrp;
      int pi = giL[r];
      f32x4 p = *(const f32x4*)(P + ((size_t)b*N_ + pi)*128 + cq);
      float dx = dxL[r][0], dy = dxL[r][1], dz = dxL[r][2];
      f32x4 y;
#pragma unroll
      for (int e=0;e<4;++e)
        y[e] = fmaf(dz, w2[e], fmaf(dy, w1[e], fmaf(dx, w0[e], p[e])));
      us4 zz;
#pragma unroll
      for (int e=0;e<4;++e)
        zz[e] = f2bf(fmaxf(fmaf(y[e], a1v[e], b1v[e]), 0.f));
      *(us4*)&Y[r*136 + cq] = zz;
    }
  }

  f32x4 acc[4][4];
  const f32x4 z4 = {0.f,0.f,0.f,0.f};
#pragma unroll
  for (int i=0;i<4;++i)
#pragma unroll
    for (int j=0;j<4;++j) acc[i][j]=z4;

  // ---------------- GEMM2 (dbuf): A = Y (z1), K=128 ----------------
  {
    bshort8 bV[2];
#pragma unroll
    for (int half=0; half<2; ++half){
      int sl = t + half*256; int r = sl>>2, p = sl&3;
      bV[half] = *(const bshort8*)(Wt2 + r*128 + p*8);
    }
#pragma unroll
    for (int half=0; half<2; ++half){
      int sl = t + half*256; int r = sl>>2, p = sl&3;
      *(bshort8*)&Bt[1][r*40+p*8] = bV[half];
    }
    for (int ch=0; ch<4; ++ch){
      const int cur = (ch & 1) ^ 1;
      __syncthreads();
      bshort8 af[4], bfr[4];
#pragma unroll
      for (int mt=0; mt<4; ++mt) af[mt]  = *(const bshort8*)&Y[(wm*64+mt*16+lrow)*136 + ch*32 + quad*8];
#pragma unroll
      for (int nt=0; nt<4; ++nt) bfr[nt] = *(const bshort8*)&Bt[cur][(wn*64+nt*16+lrow)*40 + quad*8];
      if (ch < 3){
#pragma unroll
        for (int half=0; half<2; ++half){
          int sl = t + half*256; int r = sl>>2, p = sl&3;
          bV[half] = *(const bshort8*)(Wt2 + r*128 + (ch+1)*32 + p*8);
        }
      }
#pragma unroll
      for (int mt=0; mt<4; ++mt)
#pragma unroll
        for (int nt=0; nt<4; ++nt)
          acc[mt][nt] = __builtin_amdgcn_mfma_f32_16x16x32_bf16(af[mt], bfr[nt], acc[mt][nt], 0,0,0);
      if (ch < 3){
        const int nxt = cur ^ 1;
#pragma unroll
        for (int half=0; half<2; ++half){
          int sl = t + half*256; int r = sl>>2, p = sl&3;
          *(bshort8*)&Bt[nxt][r*40+p*8] = bV[half];
        }
      }
    }
  }

  if constexpr (PHASE==2){
#pragma unroll
    for (int nt=0; nt<4; ++nt){
      float s=0.f, s2=0.f;
#pragma unroll
      for (int mt=0; mt<4; ++mt)
#pragma unroll
        for (int r=0; r<4; ++r){ float v=acc[mt][nt][r]; s+=v; s2=fmaf(v,v,s2); }
      s  += __shfl_xor(s,16,64);  s  += __shfl_xor(s,32,64);
      s2 += __shfl_xor(s2,16,64); s2 += __shfl_xor(s2,32,64);
      if (lane<16){
        int c = wn*64+nt*16+lane;
        atomicAdd(&slots[(slot*128+c)*2+0], s);
        atomicAdd(&slots[(slot*128+c)*2+1], s2);
      }
    }
    return;
  }

  if constexpr (PHASE==3){
    __syncthreads();
#pragma unroll
    for (int nt=0; nt<4; ++nt){
      int c = wn*64+nt*16+lrow;
      float sc = ss2[c], sh = ss2[128+c];
#pragma unroll
      for (int mt=0; mt<4; ++mt)
#pragma unroll
        for (int r=0; r<4; ++r){
          int row = wm*64+mt*16+quad*4+r;
          Y[row*136 + c] = f2bf(fmaxf(fmaf(acc[mt][nt][r], sc, sh), 0.f));
        }
    }

    for (int h=0; h<2; ++h){
#pragma unroll
      for (int i=0;i<4;++i)
#pragma unroll
        for (int j=0;j<4;++j) acc[i][j]=z4;
      bshort8 bV[2];
#pragma unroll
      for (int half=0; half<2; ++half){
        int sl = t + half*256; int r = sl>>2, p = sl&3;
        bV[half] = *(const bshort8*)(Wt3 + ((size_t)(h*128+r))*128 + p*8);
      }
#pragma unroll
      for (int half=0; half<2; ++half){
        int sl = t + half*256; int r = sl>>2, p = sl&3;
        *(bshort8*)&Bt[1][r*40+p*8] = bV[half];
      }
      for (int ch=0; ch<4; ++ch){
        const int cur = (ch & 1) ^ 1;
        __syncthreads();
        bshort8 af[4], bfr[4];
#pragma unroll
        for (int mt=0; mt<4; ++mt) af[mt]  = *(const bshort8*)&Y[(wm*64+mt*16+lrow)*136 + ch*32 + quad*8];
#pragma unroll
        for (int nt=0; nt<4; ++nt) bfr[nt] = *(const bshort8*)&Bt[cur][(wn*64+nt*16+lrow)*40 + quad*8];
        if (ch < 3){
#pragma unroll
          for (int half=0; half<2; ++half){
            int sl = t + half*256; int r = sl>>2, p = sl&3;
            bV[half] = *(const bshort8*)(Wt3 + ((size_t)(h*128+r))*128 + (ch+1)*32 + p*8);
          }
        }
#pragma unroll
        for (int mt=0; mt<4; ++mt)
#pragma unroll
          for (int nt=0; nt<4; ++nt)
            acc[mt][nt] = __builtin_amdgcn_mfma_f32_16x16x32_bf16(af[mt], bfr[nt], acc[mt][nt], 0,0,0);
        if (ch < 3){
          const int nxt = cur ^ 1;
#pragma unroll
          for (int half=0; half<2; ++half){
            int sl = t + half*256; int r = sl>>2, p = sl&3;
            *(bshort8*)&Bt[nxt][r*40+p*8] = bV[half];
          }
        }
      }
#pragma unroll
      for (int nt=0; nt<4; ++nt){
        float s=0.f, s2=0.f, mx=-3.0e38f, mn=3.0e38f;
#pragma unroll
        for (int mt=0; mt<4; ++mt)
#pragma unroll
          for (int r=0; r<4; ++r){
            float v=acc[mt][nt][r];
            s+=v; s2=fmaf(v,v,s2);
            mx=fmaxf(mx,v); mn=fminf(mn,v);
          }
        s  += __shfl_xor(s,16,64);  s  += __shfl_xor(s,32,64);
        s2 += __shfl_xor(s2,16,64); s2 += __shfl_xor(s2,32,64);
        mx = fmaxf(mx, __shfl_xor(mx,16,64)); mx = fmaxf(mx, __shfl_xor(mx,32,64));
        mn = fminf(mn, __shfl_xor(mn,16,64)); mn = fminf(mn, __shfl_xor(mn,32,64));
        if (lane<16){
          int c = h*128 + wn*64+nt*16+lane;
          atomicAdd(&slots[(slot*256+c)*2+0], s);
          atomicAdd(&slots[(slot*256+c)*2+1], s2);
          size_t sidx = (size_t)mblk*2 + wm;
          maxv[sidx*256 + c] = mx;
          minv[sidx*256 + c] = mn;
        }
      }
    }
  }
}

// ---------------------------------------------------------------------------
__global__ void stats_kernel(const float* __restrict__ slots, const float* __restrict__ g,
                             const float* __restrict__ beta, float* __restrict__ ssOut,
                             int C, float inv_cnt){
  int c = threadIdx.x;
  if (c >= C) return;
  float s=0.f, s2=0.f;
  for (int k=0;k<64;++k){
    s  += slots[(k*C + c)*2 + 0];
    s2 += slots[(k*C + c)*2 + 1];
  }
  float m = s * inv_cnt;
  float v = fmaxf(s2 * inv_cnt - m*m, 0.f);
  float sc = rsqrtf(v + 1e-5f) * g[c];
  ssOut[c] = sc;
  ssOut[C + c] = beta[c] - m*sc;
}

// ---------------------------------------------------------------------------
__global__ __launch_bounds__(256) void final_kernel(const float* __restrict__ minv,
                                                    const float* __restrict__ maxv,
                                                    const float* __restrict__ ss3,
                                                    float* __restrict__ out){
  __shared__ float tile[64][65];
  const int t = threadIdx.x;
  const int cb = blockIdx.x;
  const int sb = blockIdx.y;
  const int b  = blockIdx.z;
  const int w = t>>6, l = t&63;
  {
    int c = cb*64 + l;
    float sc = ss3[c], sh = ss3[256+c];
#pragma unroll
    for (int k=0;k<16;++k){
      int sl = k*4 + w;
      size_t mi = ((size_t)(b*1024 + sb*64 + sl))*256 + c;
      float v = (sc >= 0.f) ? maxv[mi] : minv[mi];
      tile[sl][l] = fmaxf(fmaf(v, sc, sh), 0.f);
    }
  }
  __syncthreads();
#pragma unroll
  for (int k=0;k<16;++k){
    int cl = k*4 + w;
    out[((size_t)(b*256 + cb*64 + cl))*1024 + sb*64 + l] = tile[l][cl];
  }
}

// ---------------------------------------------------------------------------
extern "C" void kernel_launch(void* const* d_in, const int* in_sizes, int n_in,
                              void* d_out, int out_size, void* d_ws, size_t ws_size,
                              hipStream_t stream){
  const float* xyz      = (const float*)d_in[0];
  const float* features = (const float*)d_in[1];
  const float* W1 = (const float*)d_in[2];
  const float* g1 = (const float*)d_in[3];
  const float* b1 = (const float*)d_in[4];
  const float* W2 = (const float*)d_in[5];
  const float* g2 = (const float*)d_in[6];
  const float* b2 = (const float*)d_in[7];
  const float* W3 = (const float*)d_in[8];
  const float* g3 = (const float*)d_in[9];
  const float* b3 = (const float*)d_in[10];
  float* out = (float*)d_out;

  char* ws = (char*)d_ws;
  size_t off = 0;
  auto alloc = [&](size_t bytes)->char*{
    char* p = ws + off;
    off = (off + bytes + 255) & ~(size_t)255;
    return p;
  };
  float* slots1 = (float*)alloc((size_t)64*128*2*4);
  float* slots2 = (float*)alloc((size_t)64*128*2*4);
  float* slots3 = (float*)alloc((size_t)64*256*2*4);
  float* ss1    = (float*)alloc(256*4);
  float* ss2    = (float*)alloc(256*4);
  float* ss3    = (float*)alloc(512*4);
  float* nxyz   = (float*)alloc((size_t)24576*4);
  int*   gi     = (int*)  alloc((size_t)M_*4);
  unsigned short* featT = (unsigned short*)alloc((size_t)B_*N_*CF_*2);
  unsigned short* Wt1   = (unsigned short*)alloc((size_t)128*160*2);
  unsigned short* Wt2   = (unsigned short*)alloc((size_t)128*128*2);
  unsigned short* Wt3   = (unsigned short*)alloc((size_t)256*128*2);
  float* minv = (float*)alloc((size_t)B_*S_*256*4);
  float* maxv = (float*)alloc((size_t)B_*S_*256*4);
  float* P    = (float*)alloc((size_t)B_*N_*128*4);   // 16.8 MB

  hipMemsetAsync(slots1, 0, (size_t)(64*128*2 + 64*128*2 + 64*256*2)*4, stream);

  prep_kernel<<<4160, 256, 0, stream>>>(features, W1, W2, W3, featT, Wt1, Wt2, Wt3);
  fps_pgemm_kernel<<<264, 256, 0, stream>>>(xyz, out, nxyz, featT, Wt1, P);
  qbp_y1_kernel<<<2048, 256, 0, stream>>>(xyz, nxyz, P, W1, gi, slots1);

  const float inv_cnt = 1.0f / (float)M_;
  stats_kernel<<<1, 128, 0, stream>>>(slots1, g1, b1, ss1, 128, inv_cnt);
  mm_fused<2><<<4096, 256, 0, stream>>>(P, W1, Wt2, Wt3, gi, xyz, nxyz,
                                        ss1, nullptr, slots2, nullptr, nullptr);
  stats_kernel<<<1, 128, 0, stream>>>(slots2, g2, b2, ss2, 128, inv_cnt);
  mm_fused<3><<<4096, 256, 0, stream>>>(P, W1, Wt2, Wt3, gi, xyz, nxyz,
                                        ss1, ss2, slots3, minv, maxv);
  stats_kernel<<<1, 256, 0, stream>>>(slots3, g3, b3, ss3, 256, inv_cnt);
  final_kernel<<<dim3(4,16,8), 256, 0, stream>>>(minv, maxv, ss3, out + 24576);
}

// Round 12
// 1102.320 us; speedup vs baseline: 1.2169x; 1.0220x over previous
//
#include <hip/hip_runtime.h>

#define B_  8
#define N_  4096
#define S_  1024
#define K_  64
#define CF_ 128
#define M_  (B_*S_*K_)   // 524288 rows per layer

typedef __attribute__((ext_vector_type(8))) short bshort8;
typedef __attribute__((ext_vector_type(4))) float f32x4;
typedef __attribute__((ext_vector_type(4))) int   i32x4;
typedef __attribute__((ext_vector_type(2))) float f32x2;
typedef __attribute__((ext_vector_type(4))) unsigned short us4;

__device__ __forceinline__ unsigned short f2bf(float f){
  unsigned int u = __float_as_uint(f);
  u = u + 0x7FFFu + ((u >> 16) & 1u);      // RTNE
  return (unsigned short)(u >> 16);
}
__device__ __forceinline__ float bf2f(unsigned short h){
  return __uint_as_float(((unsigned int)h) << 16);
}

// ---------------------------------------------------------------------------
// prep: transpose (blocks 0..4095) + weight prep (blocks 4096..4159)
// ---------------------------------------------------------------------------
__global__ __launch_bounds__(256) void prep_kernel(const float* __restrict__ f,
                                                   const float* __restrict__ W1,
                                                   const float* __restrict__ W2,
                                                   const float* __restrict__ W3,
                                                   unsigned short* __restrict__ ft,
                                                   unsigned short* __restrict__ Wt1,
                                                   unsigned short* __restrict__ Wt2,
                                                   unsigned short* __restrict__ Wt3){
  __shared__ float tile[32][33];
  const int blk = blockIdx.x;
  if (blk < 4096){
    int nt = blk & 127, ct = (blk>>7)&3, b = blk>>9;
    int tx = threadIdx.x & 31, ty = threadIdx.x >> 5;
#pragma unroll
    for (int r=0; r<32; r+=8)
      tile[ty+r][tx] = f[((size_t)(b*128 + ct*32 + ty + r))*4096 + nt*32 + tx];
    __syncthreads();
#pragma unroll
    for (int r=0; r<32; r+=8){
      int n = nt*32 + ty + r, cc = ct*32 + tx;
      ft[((size_t)b*4096 + n)*128 + cc] = f2bf(tile[tx][ty+r]);
    }
  } else {
    int t = (blk-4096)*256 + threadIdx.x;
    int stride = 64*256;
    for (int idx=t; idx<128*160; idx+=stride){
      int n = idx/160, k = idx-(idx/160)*160;
      float v = 0.f;
      if (k < 128) v = W1[(k+3)*128 + n];
      else if (k < 131) v = W1[(k-128)*128 + n];
      Wt1[idx] = f2bf(v);
    }
    for (int idx=t; idx<128*128; idx+=stride){
      int n = idx>>7, k = idx&127;
      Wt2[idx] = f2bf(W2[k*128+n]);
    }
    for (int idx=t; idx<256*128; idx+=stride){
      int n = idx>>7, k = idx&127;
      Wt3[idx] = f2bf(W3[k*256+n]);
    }
  }
}

// ---------------------------------------------------------------------------
// pgemm: P = featT x W1_feat (f32 out), standalone (r10 version) — runs
// BEFORE fps so fps keeps its uncontended 784us floor (r11 merge cost 28us).
// ---------------------------------------------------------------------------
__global__ __launch_bounds__(256,2) void pgemm_kernel(const unsigned short* __restrict__ featT,
                                                      const unsigned short* __restrict__ Wt1,
                                                      float* __restrict__ P){
  __shared__ alignas(16) unsigned short At[128*40];
  __shared__ alignas(16) unsigned short Bt[128*40];
  const int t = threadIdx.x, blk = blockIdx.x;     // 256 blocks
  const size_t rowBase = (size_t)blk*128;
  const int lane = t&63, wave = t>>6;
  const int wm = wave>>1, wn = wave&1;
  const int lrow = lane&15, quad = lane>>4;
  f32x4 acc[4][4];
  const f32x4 z4 = {0.f,0.f,0.f,0.f};
#pragma unroll
  for (int i=0;i<4;++i)
#pragma unroll
    for (int j=0;j<4;++j) acc[i][j]=z4;
  for (int ch=0; ch<4; ++ch){
    __syncthreads();
#pragma unroll
    for (int half=0; half<2; ++half){
      int sl = t + half*256; int r = sl>>2, p = sl&3;
      *(bshort8*)&At[r*40+p*8] = *(const bshort8*)(featT + (rowBase + r)*CF_ + ch*32 + p*8);
      *(bshort8*)&Bt[r*40+p*8] = *(const bshort8*)(Wt1 + r*160 + ch*32 + p*8);
    }
    __syncthreads();
    bshort8 af[4], bfr[4];
#pragma unroll
    for (int mt=0; mt<4; ++mt) af[mt]  = *(const bshort8*)&At[(wm*64+mt*16+lrow)*40 + quad*8];
#pragma unroll
    for (int nt=0; nt<4; ++nt) bfr[nt] = *(const bshort8*)&Bt[(wn*64+nt*16+lrow)*40 + quad*8];
#pragma unroll
    for (int mt=0; mt<4; ++mt)
#pragma unroll
      for (int nt=0; nt<4; ++nt)
        acc[mt][nt] = __builtin_amdgcn_mfma_f32_16x16x32_bf16(af[mt], bfr[nt], acc[mt][nt], 0,0,0);
  }
#pragma unroll
  for (int mt=0; mt<4; ++mt)
#pragma unroll
    for (int nt=0; nt<4; ++nt)
#pragma unroll
      for (int r=0; r<4; ++r){
        int row = wm*64 + mt*16 + quad*4 + r;
        int col = wn*64 + nt*16 + lrow;
        P[(rowBase + row)*128 + col] = acc[mt][nt][r];
      }
}

// ---------------------------------------------------------------------------
// FPS: EXACT r7/r10 version (measured floor 784us). DO NOT TOUCH.
// ---------------------------------------------------------------------------
#define DPP_PAIR_STEP(CTRL)                                                     \
  {                                                                             \
    int _vi = __builtin_amdgcn_update_dpp(__float_as_int(best), __float_as_int(best), (CTRL), 0xF, 0xF, false); \
    int _ii = __builtin_amdgcn_update_dpp(bidx, bidx, (CTRL), 0xF, 0xF, false); \
    float _ov = __int_as_float(_vi);                                            \
    bool _tk = (_ov > best) || (_ov == best && _ii < bidx);                     \
    best = _tk ? _ov : best;                                                    \
    bidx = _tk ? _ii : bidx;                                                    \
  }

__global__ __launch_bounds__(256) void fps_kernel(const float* __restrict__ xyz,
                                                  float* __restrict__ nx_out,
                                                  float* __restrict__ nx_ws){
#pragma clang fp contract(off)
  __shared__ float sx[N_], sy[N_], sz[N_];
  __shared__ int   sidx[S_];
  __shared__ alignas(16) float redv[2][4];
  __shared__ alignas(16) int   redi[2][4];
  const int b = blockIdx.x, t = threadIdx.x;
  const int lane = t & 63, w = t >> 6;
  const float* xb = xyz + (size_t)b*N_*3;
  f32x2 px[8], py[8], pz[8], dist[8];
#pragma unroll
  for (int j=0;j<8;++j){
    int i0 = (2*j)*256 + t, i1 = (2*j+1)*256 + t;
    float x0=xb[i0*3+0], y0=xb[i0*3+1], z0=xb[i0*3+2];
    float x1=xb[i1*3+0], y1=xb[i1*3+1], z1=xb[i1*3+2];
    px[j] = (f32x2){x0,x1}; py[j] = (f32x2){y0,y1}; pz[j] = (f32x2){z0,z1};
    dist[j] = (f32x2){1e10f,1e10f};
    sx[i0]=x0; sy[i0]=y0; sz[i0]=z0;
    sx[i1]=x1; sy[i1]=y1; sz[i1]=z1;
  }
  __syncthreads();
  int farthest = 0;
  for (int it=0; it<S_; ++it){
    if (t==0) sidx[it] = farthest;
    float cx = sx[farthest], cy = sy[farthest], cz = sz[farthest];
    f32x2 cx2 = (f32x2){cx,cx}, cy2 = (f32x2){cy,cy}, cz2 = (f32x2){cz,cz};
    float best = -1.0f; int bidx = 0;
#pragma unroll
    for (int j=0;j<8;++j){
      f32x2 dx = px[j] - cx2;
      f32x2 dy = py[j] - cy2;
      f32x2 dz = pz[j] - cz2;
      f32x2 d  = (dx*dx + dy*dy) + dz*dz;
      f32x2 nd;
      nd.x = fminf(dist[j].x, d.x);
      nd.y = fminf(dist[j].y, d.y);
      dist[j] = nd;
      bool tk0 = nd.x > best;
      best = tk0 ? nd.x : best;
      bidx = tk0 ? ((2*j)*256 + t) : bidx;
      bool tk1 = nd.y > best;
      best = tk1 ? nd.y : best;
      bidx = tk1 ? ((2*j+1)*256 + t) : bidx;
    }
    DPP_PAIR_STEP(0xB1);
    DPP_PAIR_STEP(0x4E);
    DPP_PAIR_STEP(0x124);
    DPP_PAIR_STEP(0x128);
    DPP_PAIR_STEP(0x142);
    DPP_PAIR_STEP(0x143);
    const int buf = it & 1;
    if (lane == 63){ redv[buf][w] = best; redi[buf][w] = bidx; }
    __syncthreads();
    f32x4 vv = *(const f32x4*)&redv[buf][0];
    i32x4 iv = *(const i32x4*)&redi[buf][0];
    float v01 = vv[0]; int i01 = iv[0];
    { bool tk = (vv[1] > v01) || (vv[1] == v01 && iv[1] < i01); v01 = tk?vv[1]:v01; i01 = tk?iv[1]:i01; }
    float v23 = vv[2]; int i23 = iv[2];
    { bool tk = (vv[3] > v23) || (vv[3] == v23 && iv[3] < i23); v23 = tk?vv[3]:v23; i23 = tk?iv[3]:i23; }
    { bool tk = (v23 > v01) || (v23 == v01 && i23 < i01); v01 = tk?v23:v01; i01 = tk?i23:i01; }
    farthest = i01;
  }
  __syncthreads();
  for (int i=t; i<S_; i+=256){
    int id = sidx[i];
    size_t base = (size_t)(b*S_+i)*3;
    float vx=sx[id], vy=sy[id], vz=sz[id];
    nx_out[base+0]=vx; nx_out[base+1]=vy; nx_out[base+2]=vz;
    nx_ws[base+0]=vx;  nx_ws[base+1]=vy;  nx_ws[base+2]=vz;
  }
}

// ---------------------------------------------------------------------------
// qbp + y1 column stats fused (unchanged from passing r11).
// ---------------------------------------------------------------------------
__global__ __launch_bounds__(256) void qbp_y1_kernel(const float* __restrict__ xyz,
                                                     const float* __restrict__ nx,
                                                     const float* __restrict__ P,
                                                     const float* __restrict__ W1,
                                                     int* __restrict__ gi,
                                                     float* __restrict__ slots){
  __shared__ int giW[4][64];
  __shared__ alignas(16) float dxL[4][64][4];
  __shared__ float sLDS[128], s2LDS[128];
  const int t = threadIdx.x;
  const int lane = t & 63, w = t >> 6;
  if (t < 128){ sLDS[t]=0.f; s2LDS[t]=0.f; }
  __syncthreads();
  const int wid = blockIdx.x*4 + w;
  const int b = wid >> 10, s = wid & 1023;
  const float* xb = xyz + (size_t)b*N_*3;
  {
    const double R2 = 0.2*0.2;
    const float* c  = nx + (size_t)(b*S_+s)*3;
    double cx=(double)c[0], cy=(double)c[1], cz=(double)c[2];
    double cc = cx*cx + cy*cy + cz*cz;
    int* g = gi + (size_t)(b*S_+s)*K_;
    int count = 0, first = -1;
    for (int ch=0; ch<64 && count<K_; ++ch){
      int i = ch*64 + lane;
      double x = (double)xb[i*3+0], y = (double)xb[i*3+1], z = (double)xb[i*3+2];
      double e  = cx*x + cy*y + cz*z;
      double pp = x*x + y*y + z*z;
      double d  = -2.0*e + cc + pp;
      bool keep = !(d > R2);
      unsigned long long bal = __ballot(keep);
      int pos = count + __builtin_popcountll(bal & ((1ull<<lane)-1ull));
      if (keep && pos < K_){ g[pos] = i; giW[w][pos] = i; }
      if (first < 0 && bal) first = ch*64 + (int)__builtin_ctzll(bal);
      count += __builtin_popcountll(bal);
    }
    if (count < K_){
      int p = count + lane;
      if (p < K_){ g[p] = first; giW[w][p] = first; }
    }
    int i = giW[w][lane];
    const float* pp = xyz + ((size_t)b*N_ + i)*3;
    const float* qq = nx  + (size_t)(b*S_ + s)*3;
    dxL[w][lane][0] = __fsub_rn(pp[0],qq[0]);
    dxL[w][lane][1] = __fsub_rn(pp[1],qq[1]);
    dxL[w][lane][2] = __fsub_rn(pp[2],qq[2]);
  }
  {
    const int cq = lane*2;
    f32x2 w0 = *(const f32x2*)(W1 + cq);
    f32x2 w1v = *(const f32x2*)(W1 + 128 + cq);
    f32x2 w2 = *(const f32x2*)(W1 + 256 + cq);
    f32x2 sA = {0,0}, s2A = {0,0};
#pragma unroll 4
    for (int r=0; r<64; ++r){
      int pi = giW[w][r];
      f32x2 p = *(const f32x2*)(P + ((size_t)b*N_ + pi)*128 + cq);
      float dx = dxL[w][r][0], dy = dxL[w][r][1], dz = dxL[w][r][2];
      f32x2 y;
#pragma unroll
      for (int e=0;e<2;++e)
        y[e] = fmaf(dz, w2[e], fmaf(dy, w1v[e], fmaf(dx, w0[e], p[e])));
      sA.x += y.x; sA.y += y.y;
      s2A.x = fmaf(y.x,y.x,s2A.x); s2A.y = fmaf(y.y,y.y,s2A.y);
    }
    atomicAdd(&sLDS[cq],    sA.x);  atomicAdd(&sLDS[cq+1],  sA.y);
    atomicAdd(&s2LDS[cq],   s2A.x); atomicAdd(&s2LDS[cq+1], s2A.y);
  }
  __syncthreads();
  if (t < 128){
    int slot = blockIdx.x & 63;
    atomicAdd(&slots[(slot*128+t)*2+0], sLDS[t]);
    atomicAdd(&slots[(slot*128+t)*2+1], s2LDS[t]);
  }
}

// ---------------------------------------------------------------------------
// mm_fused: PHASE 2 computes sums2 (+ optional raw-y2 bf16 store for STOREY2);
// PHASE 3 (fallback, r11-exact) recomputes y1->GEMM2 then GEMM3.
// ---------------------------------------------------------------------------
template<int PHASE, bool STOREY2>
__global__ __launch_bounds__(256,2) void mm_fused(
    const float* __restrict__ P,
    const float* __restrict__ W1,
    const unsigned short* __restrict__ Wt2,
    const unsigned short* __restrict__ Wt3,
    const int* __restrict__ gi,
    const float* __restrict__ xyz,
    const float* __restrict__ nxyz,
    const float* __restrict__ ss1,
    const float* __restrict__ ss2,
    float* __restrict__ slots,
    float* __restrict__ minv,
    float* __restrict__ maxv,
    unsigned short* __restrict__ y2out)
{
  __shared__ alignas(16) unsigned short Bt[2][128*40];
  __shared__ alignas(16) unsigned short Y[128*136];
  __shared__ int giL[128];
  __shared__ alignas(16) float dxL[128][4];
  __shared__ alignas(16) float w0L[128], w1L[128], w2L[128];

  const int t = threadIdx.x;
  const int mblk = blockIdx.x;
  const int b = mblk >> 9;
  const int lane = t&63, wave = t>>6;
  const int wm = wave>>1, wn = wave&1;
  const int lrow = lane&15, quad = lane>>4;
  const int slot = mblk & 63;

  if (t<128){
    int i = gi[(size_t)mblk*128 + t];
    giL[t] = i;
    int s = ((mblk*128 + t) >> 6) & 1023;
    const float* pp = xyz  + ((size_t)b*N_ + i)*3;
    const float* qq = nxyz + (size_t)(b*S_ + s)*3;
    dxL[t][0] = __fsub_rn(pp[0],qq[0]);
    dxL[t][1] = __fsub_rn(pp[1],qq[1]);
    dxL[t][2] = __fsub_rn(pp[2],qq[2]);
    w0L[t] = W1[t]; w1L[t] = W1[128+t]; w2L[t] = W1[256+t];
  }
  __syncthreads();

  // ---- y1 + BN1 + ReLU -> Y ----
  {
    const int rgrp = t>>5, cq = (t&31)*4;
    f32x4 w0 = *(const f32x4*)&w0L[cq];
    f32x4 w1 = *(const f32x4*)&w1L[cq];
    f32x4 w2 = *(const f32x4*)&w2L[cq];
    f32x4 a1v = *(const f32x4*)(ss1 + cq);
    f32x4 b1v = *(const f32x4*)(ss1 + 128 + cq);
#pragma unroll
    for (int g=0; g<16; ++g){
      int r = g*8 + rgrp;
      int pi = giL[r];
      f32x4 p = *(const f32x4*)(P + ((size_t)b*N_ + pi)*128 + cq);
      float dx = dxL[r][0], dy = dxL[r][1], dz = dxL[r][2];
      f32x4 y;
#pragma unroll
      for (int e=0;e<4;++e)
        y[e] = fmaf(dz, w2[e], fmaf(dy, w1[e], fmaf(dx, w0[e], p[e])));
      us4 zz;
#pragma unroll
      for (int e=0;e<4;++e)
        zz[e] = f2bf(fmaxf(fmaf(y[e], a1v[e], b1v[e]), 0.f));
      *(us4*)&Y[r*136 + cq] = zz;
    }
  }

  f32x4 acc[4][4];
  const f32x4 z4 = {0.f,0.f,0.f,0.f};
#pragma unroll
  for (int i=0;i<4;++i)
#pragma unroll
    for (int j=0;j<4;++j) acc[i][j]=z4;

  // ---------------- GEMM2 (dbuf): A = Y (z1), K=128 ----------------
  {
    bshort8 bV[2];
#pragma unroll
    for (int half=0; half<2; ++half){
      int sl = t + half*256; int r = sl>>2, p = sl&3;
      bV[half] = *(const bshort8*)(Wt2 + r*128 + p*8);
    }
#pragma unroll
    for (int half=0; half<2; ++half){
      int sl = t + half*256; int r = sl>>2, p = sl&3;
      *(bshort8*)&Bt[1][r*40+p*8] = bV[half];
    }
    for (int ch=0; ch<4; ++ch){
      const int cur = (ch & 1) ^ 1;
      __syncthreads();
      bshort8 af[4], bfr[4];
#pragma unroll
      for (int mt=0; mt<4; ++mt) af[mt]  = *(const bshort8*)&Y[(wm*64+mt*16+lrow)*136 + ch*32 + quad*8];
#pragma unroll
      for (int nt=0; nt<4; ++nt) bfr[nt] = *(const bshort8*)&Bt[cur][(wn*64+nt*16+lrow)*40 + quad*8];
      if (ch < 3){
#pragma unroll
        for (int half=0; half<2; ++half){
          int sl = t + half*256; int r = sl>>2, p = sl&3;
          bV[half] = *(const bshort8*)(Wt2 + r*128 + (ch+1)*32 + p*8);
        }
      }
#pragma unroll
      for (int mt=0; mt<4; ++mt)
#pragma unroll
        for (int nt=0; nt<4; ++nt)
          acc[mt][nt] = __builtin_amdgcn_mfma_f32_16x16x32_bf16(af[mt], bfr[nt], acc[mt][nt], 0,0,0);
      if (ch < 3){
        const int nxt = cur ^ 1;
#pragma unroll
        for (int half=0; half<2; ++half){
          int sl = t + half*256; int r = sl>>2, p = sl&3;
          *(bshort8*)&Bt[nxt][r*40+p*8] = bV[half];
        }
      }
    }
  }

  if constexpr (PHASE==2){
#pragma unroll
    for (int nt=0; nt<4; ++nt){
      float s=0.f, s2=0.f;
#pragma unroll
      for (int mt=0; mt<4; ++mt)
#pragma unroll
        for (int r=0; r<4; ++r){ float v=acc[mt][nt][r]; s+=v; s2=fmaf(v,v,s2); }
      s  += __shfl_xor(s,16,64);  s  += __shfl_xor(s,32,64);
      s2 += __shfl_xor(s2,16,64); s2 += __shfl_xor(s2,32,64);
      if (lane<16){
        int c = wn*64+nt*16+lane;
        atomicAdd(&slots[(slot*128+c)*2+0], s);
        atomicAdd(&slots[(slot*128+c)*2+1], s2);
      }
    }
    if constexpr (STOREY2){
      // raw y2 -> Y (bf16), then coalesced 16B stores
      __syncthreads();
#pragma unroll
      for (int nt=0; nt<4; ++nt){
        int c = wn*64+nt*16+lrow;
#pragma unroll
        for (int mt=0; mt<4; ++mt)
#pragma unroll
          for (int r=0; r<4; ++r){
            int row = wm*64+mt*16+quad*4+r;
            Y[row*136 + c] = f2bf(acc[mt][nt][r]);
          }
      }
      __syncthreads();
      for (int idx=t; idx<128*16; idx+=256){
        int r = idx>>4, p = idx&15;
        bshort8 v = *(const bshort8*)&Y[r*136 + p*8];
        *(bshort8*)(y2out + ((size_t)mblk*128 + r)*128 + p*8) = v;
      }
    }
    return;
  }

  if constexpr (PHASE==3){
    __syncthreads();
#pragma unroll
    for (int nt=0; nt<4; ++nt){
      int c = wn*64+nt*16+lrow;
      float sc = ss2[c], sh = ss2[128+c];
#pragma unroll
      for (int mt=0; mt<4; ++mt)
#pragma unroll
        for (int r=0; r<4; ++r){
          int row = wm*64+mt*16+quad*4+r;
          Y[row*136 + c] = f2bf(fmaxf(fmaf(acc[mt][nt][r], sc, sh), 0.f));
        }
    }

    for (int h=0; h<2; ++h){
#pragma unroll
      for (int i=0;i<4;++i)
#pragma unroll
        for (int j=0;j<4;++j) acc[i][j]=z4;
      bshort8 bV[2];
#pragma unroll
      for (int half=0; half<2; ++half){
        int sl = t + half*256; int r = sl>>2, p = sl&3;
        bV[half] = *(const bshort8*)(Wt3 + ((size_t)(h*128+r))*128 + p*8);
      }
#pragma unroll
      for (int half=0; half<2; ++half){
        int sl = t + half*256; int r = sl>>2, p = sl&3;
        *(bshort8*)&Bt[1][r*40+p*8] = bV[half];
      }
      for (int ch=0; ch<4; ++ch){
        const int cur = (ch & 1) ^ 1;
        __syncthreads();
        bshort8 af[4], bfr[4];
#pragma unroll
        for (int mt=0; mt<4; ++mt) af[mt]  = *(const bshort8*)&Y[(wm*64+mt*16+lrow)*136 + ch*32 + quad*8];
#pragma unroll
        for (int nt=0; nt<4; ++nt) bfr[nt] = *(const bshort8*)&Bt[cur][(wn*64+nt*16+lrow)*40 + quad*8];
        if (ch < 3){
#pragma unroll
          for (int half=0; half<2; ++half){
            int sl = t + half*256; int r = sl>>2, p = sl&3;
            bV[half] = *(const bshort8*)(Wt3 + ((size_t)(h*128+r))*128 + (ch+1)*32 + p*8);
          }
        }
#pragma unroll
        for (int mt=0; mt<4; ++mt)
#pragma unroll
          for (int nt=0; nt<4; ++nt)
            acc[mt][nt] = __builtin_amdgcn_mfma_f32_16x16x32_bf16(af[mt], bfr[nt], acc[mt][nt], 0,0,0);
        if (ch < 3){
          const int nxt = cur ^ 1;
#pragma unroll
          for (int half=0; half<2; ++half){
            int sl = t + half*256; int r = sl>>2, p = sl&3;
            *(bshort8*)&Bt[nxt][r*40+p*8] = bV[half];
          }
        }
      }
#pragma unroll
      for (int nt=0; nt<4; ++nt){
        float s=0.f, s2=0.f, mx=-3.0e38f, mn=3.0e38f;
#pragma unroll
        for (int mt=0; mt<4; ++mt)
#pragma unroll
          for (int r=0; r<4; ++r){
            float v=acc[mt][nt][r];
            s+=v; s2=fmaf(v,v,s2);
            mx=fmaxf(mx,v); mn=fminf(mn,v);
          }
        s  += __shfl_xor(s,16,64);  s  += __shfl_xor(s,32,64);
        s2 += __shfl_xor(s2,16,64); s2 += __shfl_xor(s2,32,64);
        mx = fmaxf(mx, __shfl_xor(mx,16,64)); mx = fmaxf(mx, __shfl_xor(mx,32,64));
        mn = fminf(mn, __shfl_xor(mn,16,64)); mn = fminf(mn, __shfl_xor(mn,32,64));
        if (lane<16){
          int c = h*128 + wn*64+nt*16+lane;
          atomicAdd(&slots[(slot*256+c)*2+0], s);
          atomicAdd(&slots[(slot*256+c)*2+1], s2);
          size_t sidx = (size_t)mblk*2 + wm;
          maxv[sidx*256 + c] = mx;
          minv[sidx*256 + c] = mn;
        }
      }
    }
  }
}

// ---------------------------------------------------------------------------
// mm3 (y2-load path): load raw y2 bf16, BN2+ReLU -> z2(Y), GEMM3 (2 halves).
// No gi/P/GEMM2 recompute.
// ---------------------------------------------------------------------------
__global__ __launch_bounds__(256,2) void mm3_kernel(
    const unsigned short* __restrict__ y2,
    const unsigned short* __restrict__ Wt3,
    const float* __restrict__ ss2,
    float* __restrict__ slots,
    float* __restrict__ minv,
    float* __restrict__ maxv)
{
  __shared__ alignas(16) unsigned short Bt[2][128*40];
  __shared__ alignas(16) unsigned short Y[128*136];
  const int t = threadIdx.x;
  const int mblk = blockIdx.x;
  const int lane = t&63, wave = t>>6;
  const int wm = wave>>1, wn = wave&1;
  const int lrow = lane&15, quad = lane>>4;
  const int slot = mblk & 63;

  // stage z2 = relu(y2*sc + sh) into Y
  {
    const int rgrp = t>>5, cq = (t&31)*4;
    f32x4 a2 = *(const f32x4*)(ss2 + cq);
    f32x4 b2 = *(const f32x4*)(ss2 + 128 + cq);
#pragma unroll
    for (int g=0; g<16; ++g){
      int r = g*8 + rgrp;
      us4 yv = *(const us4*)(y2 + ((size_t)mblk*128 + r)*128 + cq);
      us4 zz;
#pragma unroll
      for (int e=0;e<4;++e)
        zz[e] = f2bf(fmaxf(fmaf(bf2f(yv[e]), a2[e], b2[e]), 0.f));
      *(us4*)&Y[r*136 + cq] = zz;
    }
  }

  f32x4 acc[4][4];
  const f32x4 z4 = {0.f,0.f,0.f,0.f};
  for (int h=0; h<2; ++h){
#pragma unroll
    for (int i=0;i<4;++i)
#pragma unroll
      for (int j=0;j<4;++j) acc[i][j]=z4;
    bshort8 bV[2];
#pragma unroll
    for (int half=0; half<2; ++half){
      int sl = t + half*256; int r = sl>>2, p = sl&3;
      bV[half] = *(const bshort8*)(Wt3 + ((size_t)(h*128+r))*128 + p*8);
    }
#pragma unroll
    for (int half=0; half<2; ++half){
      int sl = t + half*256; int r = sl>>2, p = sl&3;
      *(bshort8*)&Bt[1][r*40+p*8] = bV[half];
    }
    for (int ch=0; ch<4; ++ch){
      const int cur = (ch & 1) ^ 1;
      __syncthreads();   // first iter also covers the Y staging
      bshort8 af[4], bfr[4];
#pragma unroll
      for (int mt=0; mt<4; ++mt) af[mt]  = *(const bshort8*)&Y[(wm*64+mt*16+lrow)*136 + ch*32 + quad*8];
#pragma unroll
      for (int nt=0; nt<4; ++nt) bfr[nt] = *(const bshort8*)&Bt[cur][(wn*64+nt*16+lrow)*40 + quad*8];
      if (ch < 3){
#pragma unroll
        for (int half=0; half<2; ++half){
          int sl = t + half*256; int r = sl>>2, p = sl&3;
          bV[half] = *(const bshort8*)(Wt3 + ((size_t)(h*128+r))*128 + (ch+1)*32 + p*8);
        }
      }
#pragma unroll
      for (int mt=0; mt<4; ++mt)
#pragma unroll
        for (int nt=0; nt<4; ++nt)
          acc[mt][nt] = __builtin_amdgcn_mfma_f32_16x16x32_bf16(af[mt], bfr[nt], acc[mt][nt], 0,0,0);
      if (ch < 3){
        const int nxt = cur ^ 1;
#pragma unroll
        for (int half=0; half<2; ++half){
          int sl = t + half*256; int r = sl>>2, p = sl&3;
          *(bshort8*)&Bt[nxt][r*40+p*8] = bV[half];
        }
      }
    }
#pragma unroll
    for (int nt=0; nt<4; ++nt){
      float s=0.f, s2=0.f, mx=-3.0e38f, mn=3.0e38f;
#pragma unroll
      for (int mt=0; mt<4; ++mt)
#pragma unroll
        for (int r=0; r<4; ++r){
          float v=acc[mt][nt][r];
          s+=v; s2=fmaf(v,v,s2);
          mx=fmaxf(mx,v); mn=fminf(mn,v);
        }
      s  += __shfl_xor(s,16,64);  s  += __shfl_xor(s,32,64);
      s2 += __shfl_xor(s2,16,64); s2 += __shfl_xor(s2,32,64);
      mx = fmaxf(mx, __shfl_xor(mx,16,64)); mx = fmaxf(mx, __shfl_xor(mx,32,64));
      mn = fminf(mn, __shfl_xor(mn,16,64)); mn = fminf(mn, __shfl_xor(mn,32,64));
      if (lane<16){
        int c = h*128 + wn*64+nt*16+lane;
        atomicAdd(&slots[(slot*256+c)*2+0], s);
        atomicAdd(&slots[(slot*256+c)*2+1], s2);
        size_t sidx = (size_t)mblk*2 + wm;
        maxv[sidx*256 + c] = mx;
        minv[sidx*256 + c] = mn;
      }
    }
    if (h==0) __syncthreads();   // protect Y reads vs nothing (Y unchanged) — keeps parity
  }
}

// ---------------------------------------------------------------------------
__global__ void stats_kernel(const float* __restrict__ slots, const float* __restrict__ g,
                             const float* __restrict__ beta, float* __restrict__ ssOut,
                             int C, float inv_cnt){
  int c = threadIdx.x;
  if (c >= C) return;
  float s=0.f, s2=0.f;
  for (int k=0;k<64;++k){
    s  += slots[(k*C + c)*2 + 0];
    s2 += slots[(k*C + c)*2 + 1];
  }
  float m = s * inv_cnt;
  float v = fmaxf(s2 * inv_cnt - m*m, 0.f);
  float sc = rsqrtf(v + 1e-5f) * g[c];
  ssOut[c] = sc;
  ssOut[C + c] = beta[c] - m*sc;
}

// ---------------------------------------------------------------------------
__global__ __launch_bounds__(256) void final_kernel(const float* __restrict__ minv,
                                                    const float* __restrict__ maxv,
                                                    const float* __restrict__ ss3,
                                                    float* __restrict__ out){
  __shared__ float tile[64][65];
  const int t = threadIdx.x;
  const int cb = blockIdx.x;
  const int sb = blockIdx.y;
  const int b  = blockIdx.z;
  const int w = t>>6, l = t&63;
  {
    int c = cb*64 + l;
    float sc = ss3[c], sh = ss3[256+c];
#pragma unroll
    for (int k=0;k<16;++k){
      int sl = k*4 + w;
      size_t mi = ((size_t)(b*1024 + sb*64 + sl))*256 + c;
      float v = (sc >= 0.f) ? maxv[mi] : minv[mi];
      tile[sl][l] = fmaxf(fmaf(v, sc, sh), 0.f);
    }
  }
  __syncthreads();
#pragma unroll
  for (int k=0;k<16;++k){
    int cl = k*4 + w;
    out[((size_t)(b*256 + cb*64 + cl))*1024 + sb*64 + l] = tile[l][cl];
  }
}

// ---------------------------------------------------------------------------
extern "C" void kernel_launch(void* const* d_in, const int* in_sizes, int n_in,
                              void* d_out, int out_size, void* d_ws, size_t ws_size,
                              hipStream_t stream){
  const float* xyz      = (const float*)d_in[0];
  const float* features = (const float*)d_in[1];
  const float* W1 = (const float*)d_in[2];
  const float* g1 = (const float*)d_in[3];
  const float* b1 = (const float*)d_in[4];
  const float* W2 = (const float*)d_in[5];
  const float* g2 = (const float*)d_in[6];
  const float* b2 = (const float*)d_in[7];
  const float* W3 = (const float*)d_in[8];
  const float* g3 = (const float*)d_in[9];
  const float* b3 = (const float*)d_in[10];
  float* out = (float*)d_out;

  char* ws = (char*)d_ws;
  size_t off = 0;
  auto alloc = [&](size_t bytes)->char*{
    char* p = ws + off;
    off = (off + bytes + 255) & ~(size_t)255;
    return p;
  };
  float* slots1 = (float*)alloc((size_t)64*128*2*4);
  float* slots2 = (float*)alloc((size_t)64*128*2*4);
  float* slots3 = (float*)alloc((size_t)64*256*2*4);
  float* ss1    = (float*)alloc(256*4);
  float* ss2    = (float*)alloc(256*4);
  float* ss3    = (float*)alloc(512*4);
  float* nxyz   = (float*)alloc((size_t)24576*4);
  int*   gi     = (int*)  alloc((size_t)M_*4);
  unsigned short* featT = (unsigned short*)alloc((size_t)B_*N_*CF_*2);
  unsigned short* Wt1   = (unsigned short*)alloc((size_t)128*160*2);
  unsigned short* Wt2   = (unsigned short*)alloc((size_t)128*128*2);
  unsigned short* Wt3   = (unsigned short*)alloc((size_t)256*128*2);
  float* minv = (float*)alloc((size_t)B_*S_*256*4);
  float* maxv = (float*)alloc((size_t)B_*S_*256*4);
  float* P    = (float*)alloc((size_t)B_*N_*128*4);   // 16.8 MB
  size_t base_end = off;
  unsigned short* y2 = (unsigned short*)alloc((size_t)M_*128*2);  // 134 MB
  const bool bigws = (off <= ws_size);   // constant across calls -> capture-safe
  (void)base_end;

  hipMemsetAsync(slots1, 0, (size_t)(64*128*2 + 64*128*2 + 64*256*2)*4, stream);

  prep_kernel<<<4160, 256, 0, stream>>>(features, W1, W2, W3, featT, Wt1, Wt2, Wt3);
  pgemm_kernel<<<256, 256, 0, stream>>>(featT, Wt1, P);
  fps_kernel<<<8, 256, 0, stream>>>(xyz, out, nxyz);
  qbp_y1_kernel<<<2048, 256, 0, stream>>>(xyz, nxyz, P, W1, gi, slots1);

  const float inv_cnt = 1.0f / (float)M_;
  stats_kernel<<<1, 128, 0, stream>>>(slots1, g1, b1, ss1, 128, inv_cnt);
  if (bigws){
    mm_fused<2,true><<<4096, 256, 0, stream>>>(P, W1, Wt2, Wt3, gi, xyz, nxyz,
                                               ss1, nullptr, slots2, nullptr, nullptr, y2);
    stats_kernel<<<1, 128, 0, stream>>>(slots2, g2, b2, ss2, 128, inv_cnt);
    mm3_kernel<<<4096, 256, 0, stream>>>(y2, Wt3, ss2, slots3, minv, maxv);
  } else {
    mm_fused<2,false><<<4096, 256, 0, stream>>>(P, W1, Wt2, Wt3, gi, xyz, nxyz,
                                                ss1, nullptr, slots2, nullptr, nullptr, nullptr);
    stats_kernel<<<1, 128, 0, stream>>>(slots2, g2, b2, ss2, 128, inv_cnt);
    mm_fused<3,false><<<4096, 256, 0, stream>>>(P, W1, Wt2, Wt3, gi, xyz, nxyz,
                                                ss1, ss2, slots3, minv, maxv, nullptr);
  }
  stats_kernel<<<1, 256, 0, stream>>>(slots3, g3, b3, ss3, 256, inv_cnt);
  final_kernel<<<dim3(4,16,8), 256, 0, stream>>>(minv, maxv, ss3, out + 24576);
}